// Round 12
// baseline (319.721 us; speedup 1.0000x reference)
//
#include <hip/hip_runtime.h>
#include <hip/hip_fp16.h>
#include <math.h>

#define NN    50000
#define INF_  256
#define HID   64
#define OUTF  32
#define EE    800000
#define TOTN  (3 * NN)
#define NBKT  196
#define NBIN  (3 * NBKT)     // 588
#define CBLK  392
#define NCNT  (3 * CBLK)     // 1176
#define GB    782
#define NGEMM (3 * GB)       // 2346
#define MAXB  5120
#define NBLK  12500          // node-blocks per branch (4 nodes each)

typedef unsigned long long u64;
typedef unsigned int       u32;
typedef unsigned short     u16;
typedef _Float16           f16;
typedef f16   f16x8 __attribute__((ext_vector_type(8)));
typedef f16   f16x4 __attribute__((ext_vector_type(4)));
typedef float f32x4 __attribute__((ext_vector_type(4)));

// ---------------- prep: zero bin totals + transpose/convert W -> Wt fp16 [col][k] ----------------
__global__ __launch_bounds__(256) void k_prep(
        const float* __restrict__ W1, const float* __restrict__ W2, const float* __restrict__ W3,
        f16* __restrict__ Wt, u32* __restrict__ bin_total) {
    int blk = blockIdx.x, t = threadIdx.x;
    if (blk == 3) {
        for (int i = t; i < NBIN; i += 256) bin_total[i] = 0;
        return;
    }
    const float* W = (blk == 0) ? W1 : (blk == 1) ? W2 : W3;
    f16* wt = Wt + blk * HID * INF_;
    for (int idx = t; idx < INF_ * HID; idx += 256) {
        int k = idx >> 6, c = idx & 63;
        wt[c * INF_ + k] = (f16)W[idx];
    }
}

// ---------------- fused: bucket-count + barrier-free MFMA gemm, 2:1 interleave ----------------
// gemm path: NO LDS, NO barriers. A-frags direct from x (fp32->f16 cvt in VALU),
// B-frags direct from Wt (32 KB/branch, L1/L2-resident). 48 indep loads/lane in flight.
__global__ __launch_bounds__(256) void k_cntgemm(
        const int* __restrict__ ei1, const int* __restrict__ ei2, const int* __restrict__ ei3,
        u32* __restrict__ bin_total, u32* __restrict__ blockbase,
        const float* __restrict__ x1, const float* __restrict__ x2, const float* __restrict__ x3,
        const f16* __restrict__ Wt, __half* __restrict__ h) {
    __shared__ u32 bins[NBKT];
    int bid = blockIdx.x;
    int q = bid / 3, r = bid - q * 3;
    int t = threadIdx.x;

    if (r == 2) {                   // ---- count block: q in [0,1176) ----
        int cb  = q;
        int br  = cb / CBLK;
        int blk = cb - br * CBLK;
        const int* ei = (br == 0) ? ei1 : (br == 1) ? ei2 : ei3;
        for (int i = t; i < NBKT; i += 256) bins[i] = 0;
        __syncthreads();
        int e0 = blk * 2048;
#pragma unroll
        for (int k = 0; k < 8; ++k) {
            int e = e0 + k * 256 + t;
            if (e < EE) atomicAdd(&bins[(u32)ei[EE + e] >> 8], 1u);
        }
        __syncthreads();
        for (int i = t; i < NBKT; i += 256) {
            u32 c = bins[i];
            u32 base = atomicAdd(&bin_total[br * NBKT + i], c);
            blockbase[cb * NBKT + i] = base;
        }
        return;
    }

    // ---- gemm: gid in [0, NGEMM) ----
    int gid = q * 2 + r;
    if (gid >= NGEMM) return;
    int b = gid / GB;
    int row_base = (gid - b * GB) * 64;
    const float* x = (b == 0) ? x1 : (b == 1) ? x2 : x3;
    const f16* wt = Wt + b * HID * INF_;
    __half* hb = h + (size_t)b * NN * HID;

    int w    = t >> 6;
    int lane = t & 63;
    int lrow = lane & 15;
    int lk   = (lane >> 4) * 8;      // k-offset within 32-step

    int arow  = row_base + (w << 4) + lrow;
    int arowc = arow < NN ? arow : NN - 1;          // clamp for load; stores guarded
    const float4* xr = reinterpret_cast<const float4*>(x + (size_t)arowc * INF_);

    f32x4 acc[4] = {{0,0,0,0},{0,0,0,0},{0,0,0,0},{0,0,0,0}};
#pragma unroll
    for (int kt = 0; kt < 8; ++kt) {                // K-step 32, fully unrolled
        float4 a0 = xr[kt * 8 + (lk >> 2)];
        float4 a1 = xr[kt * 8 + (lk >> 2) + 1];
        f16x8 af = {(f16)a0.x, (f16)a0.y, (f16)a0.z, (f16)a0.w,
                    (f16)a1.x, (f16)a1.y, (f16)a1.z, (f16)a1.w};
#pragma unroll
        for (int c = 0; c < 4; ++c) {
            f16x8 bf = *(const f16x8*)&wt[(c * 16 + lrow) * INF_ + kt * 32 + lk];
            acc[c] = __builtin_amdgcn_mfma_f32_16x16x32_f16(af, bf, acc[c], 0, 0, 0);
        }
    }
    int orow0 = row_base + (w << 4) + ((lane >> 4) << 2);
#pragma unroll
    for (int c = 0; c < 4; ++c) {
#pragma unroll
        for (int i = 0; i < 4; ++i) {
            int row = orow0 + i;
            if (row < NN) hb[(size_t)row * HID + c * 16 + lrow] = __float2half(acc[c][i]);
        }
    }
}

// ---------------- parallel scan of 588 bucket totals ----------------
__global__ __launch_bounds__(256) void k_scan(const u32* __restrict__ bin_total,
                                              u32* __restrict__ binstart) {
    __shared__ u32 s[256];
    int t = threadIdx.x;
    u32 c[3]; u32 sum = 0;
#pragma unroll
    for (int k = 0; k < 3; ++k) {
        int i = t * 3 + k;
        c[k] = (i < NBIN) ? bin_total[i] : 0;
        sum += c[k];
    }
    s[t] = sum;
    __syncthreads();
    for (int d = 1; d < 256; d <<= 1) {
        u32 v = (t >= d) ? s[t - d] : 0;
        __syncthreads();
        s[t] += v;
        __syncthreads();
    }
    u32 run = s[t] - sum;
#pragma unroll
    for (int k = 0; k < 3; ++k) {
        int i = t * 3 + k;
        if (i < NBIN) binstart[i] = run;
        run += c[k];
    }
    if (t == 255) binstart[NBIN] = run;
}

// ---------------- scatter edges into bucket-contiguous regions ----------------
__global__ __launch_bounds__(256) void k_scatter(
        const int* __restrict__ ei1, const int* __restrict__ ei2, const int* __restrict__ ei3,
        const float* __restrict__ ew1, const float* __restrict__ ew2, const float* __restrict__ ew3,
        const u32* __restrict__ binstart, const u32* __restrict__ blockbase,
        u64* __restrict__ bucketed) {
    __shared__ u32 cur[NBKT];
    int cb  = blockIdx.x;
    int br  = cb / CBLK;
    int blk = cb - br * CBLK;
    const int*   ei = (br == 0) ? ei1 : (br == 1) ? ei2 : ei3;
    const float* ew = (br == 0) ? ew1 : (br == 1) ? ew2 : ew3;
    int t = threadIdx.x;
    for (int i = t; i < NBKT; i += 256) cur[i] = 0;
    __syncthreads();
    int e0 = blk * 2048;
#pragma unroll
    for (int k = 0; k < 8; ++k) {
        int e = e0 + k * 256 + t;
        if (e < EE) {
            u32 dst = (u32)ei[EE + e];
            u32 src = (u32)ei[e];
            u32 bkt = dst >> 8;
            u32 rnk = atomicAdd(&cur[bkt], 1u);
            u32 pos = binstart[br * NBKT + bkt] + blockbase[cb * NBKT + bkt] + rnk;
            bucketed[pos] = ((u64)__float_as_uint(ew[e]) << 32) | (src << 8) | (dst & 0xffu);
        }
    }
}

// ---------------- per-bucket: nodeinfo/dinv/CSR in LDS + h-prescale of owned rows ----------------
__global__ __launch_bounds__(256) void k_bucket(
        const u64* __restrict__ bucketed, const u32* __restrict__ bin_total,
        const u32* __restrict__ binstart,
        u32* __restrict__ nodeinfo, float* __restrict__ dinv,
        u32* __restrict__ csr, __half* __restrict__ h) {
    __shared__ u32   scnt[256];
    __shared__ float swsum[256];
    __shared__ u32   scur[256];
    __shared__ u32   sscan[256];
    __shared__ float sdiv[256];
    __shared__ u32   lcsr[MAXB];
    int bin = blockIdx.x;
    int br  = bin / NBKT;
    int bkt = bin - br * NBKT;
    int t = threadIdx.x;
    u32 base = binstart[bin];
    u32 ecnt = bin_total[bin];
    scnt[t] = 0; swsum[t] = 0.f; scur[t] = 0;
    __syncthreads();
    for (u32 i = t; i < ecnt; i += 256) {
        u64 e = bucketed[base + i];
        u32 dl = (u32)e & 0xffu;
        atomicAdd(&scnt[dl], 1u);
        atomicAdd(&swsum[dl], __uint_as_float((u32)(e >> 32)));
    }
    __syncthreads();
    sscan[t] = scnt[t];
    __syncthreads();
    for (int d = 1; d < 256; d <<= 1) {
        u32 v = (t >= d) ? sscan[t - d] : 0;
        __syncthreads();
        sscan[t] += v;
        __syncthreads();
    }
    u32 lstart = sscan[t] - scnt[t];
    float d = rsqrtf(1.0f + swsum[t]);
    sdiv[t] = d;
    int n = bkt * 256 + t;
    if (n < NN) {
        int gi = br * NN + n;
        nodeinfo[gi] = ((base + lstart) << 10) | scnt[t];
        dinv[gi]     = d;
    }
    __syncthreads();
    for (u32 i = t; i < ecnt; i += 256) {
        u64 e = bucketed[base + i];
        u32 dl  = (u32)e & 0xffu;
        u32 src = (u32)(e >> 8) & 0xffffu;
        float w = __uint_as_float((u32)(e >> 32));
        u32 rnk = atomicAdd(&scur[dl], 1u);
        u32 ls  = sscan[dl] - scnt[dl];
        lcsr[ls + rnk] = ((u32)__half_as_ushort(__float2half(w)) << 16) | src;
    }
    __syncthreads();
    for (u32 i = t; i < ecnt; i += 256) csr[base + i] = lcsr[i];

    int nrows = NN - bkt * 256; if (nrows > 256) nrows = 256;
    u32* hrow = (u32*)(h + ((size_t)br * NN + (size_t)bkt * 256) * HID);
    for (int i = t; i < nrows * 32; i += 256) {
        float dd = sdiv[i >> 5];
        __half2 hv = *(__half2*)&hrow[i];
        float2 v = __half22float2(hv);
        __half2 r = __float22half2_rn(make_float2(v.x * dd, v.y * dd));
        hrow[i] = *(u32*)&r;
    }
}

// ---------------- layer-1 aggregation, BRANCH-MAJOR (L2 phase residency): e = ReLU(...) ----------------
__global__ __launch_bounds__(256) void k_agg1(
        const u32* __restrict__ csr, const u32* __restrict__ nodeinfo,
        const float* __restrict__ dinv,
        const float* __restrict__ b1, const float* __restrict__ b2, const float* __restrict__ b3,
        const __half* __restrict__ h, __half* __restrict__ e) {
    int bid = blockIdx.x;
    int br  = bid / NBLK;
    int nb  = bid - br * NBLK;
    int t   = threadIdx.x;
    int f2  = t & 31;
    int eo  = (t >> 5) & 1;
    int sub = __builtin_amdgcn_readfirstlane(t >> 6);
    int n   = nb * 4 + sub;

    const float* bi = (br == 0) ? b1 : (br == 1) ? b2 : b3;
    const __half2* hb2 = (const __half2*)(h + (size_t)br * NN * HID);
    int i   = br * NN + n;
    u32 inf = nodeinfo[i];
    int cc  = (int)(inf & 1023u);
    int st  = (int)(inf >> 10);
    float d = dinv[i];
    float2 hs = __half22float2(hb2[(size_t)n * 32 + f2]);

    float ax = 0.f, ay = 0.f;
    int cm1 = cc - 1;
    for (int j = 0; j < cc; j += 16) {
        u32 ee[8]; __half2 vv[8];
#pragma unroll
        for (int u = 0; u < 8; ++u) {
            int jj = j + 2 * u + eo;
            ee[u] = csr[st + (jj < cm1 ? jj : cm1)];
            if (jj >= cc) ee[u] &= 0xffffu;
        }
#pragma unroll
        for (int u = 0; u < 8; ++u)
            vv[u] = hb2[(size_t)(ee[u] & 0xffff) * 32 + f2];
#pragma unroll
        for (int u = 0; u < 8; ++u) {
            float w = __half2float(__ushort_as_half((u16)(ee[u] >> 16)));
            float2 v = __half22float2(vv[u]);
            ax = fmaf(w, v.x, ax);
            ay = fmaf(w, v.y, ay);
        }
    }
    ax += __shfl_xor(ax, 32);
    ay += __shfl_xor(ay, 32);
    float2 bv = ((const float2*)bi)[f2];
    float ex = fmaxf(bv.x + d * (hs.x + ax), 0.f);
    float ey = fmaxf(bv.y + d * (hs.y + ay), 0.f);
    if (eo == 0)
        ((__half2*)e)[((size_t)br * NN + n) * 32 + f2] = __float22half2_rn(make_float2(ex, ey));
}

// ---------------- attention: coefs + comb from e (sequential reads) ----------------
__global__ __launch_bounds__(256) void k_attn(
        const __half* __restrict__ e,
        const float* __restrict__ fc_w, const float* __restrict__ fc_b,
        __half* __restrict__ comb, float* __restrict__ coef_out) {
    int t    = threadIdx.x;
    int lane = t & 63;
    int sub  = __builtin_amdgcn_readfirstlane(t >> 6);
    int half = lane >> 5;
    int f2   = lane & 31;
    int n    = blockIdx.x * 8 + sub * 2 + half;
    float2 wv = ((const float2*)fc_w)[f2];
    float fb = fc_b[0];
    const __half2* e2 = (const __half2*)e;

    float2 ev[3]; float c[3];
#pragma unroll
    for (int b = 0; b < 3; ++b) {
        ev[b] = __half22float2(e2[((size_t)b * NN + n) * 32 + f2]);
        float dd = ev[b].x * wv.x + ev[b].y * wv.y;
#pragma unroll
        for (int off = 16; off > 0; off >>= 1) dd += __shfl_xor(dd, off);
        float z = dd + fb;
        z = (z > 0.f) ? z : 0.01f * z;
        c[b] = expf(z);
    }
    float cd = c[0] + c[1] + c[2];
    float coef0 = c[0] / cd, coef1 = c[1] / cd, coef2 = c[2] / cd;
    float cx = ev[0].x * coef0 + ev[1].x * coef1 + ev[2].x * coef2;
    float cy = ev[0].y * coef0 + ev[1].y * coef1 + ev[2].y * coef2;
    ((__half2*)comb)[(size_t)n * 32 + f2] = __float22half2_rn(make_float2(cx, cy));
    if (f2 == 0) {
        coef_out[n]          = coef0;
        coef_out[NN + n]     = coef1;
        coef_out[2 * NN + n] = coef2;
    }
}

// ---------------- layer-2 GEMM: h2'[b] = dinv * (comb @ W_b) ----------------
__global__ __launch_bounds__(256) void k_gemm2(
        const __half* __restrict__ comb,
        const float* __restrict__ W11, const float* __restrict__ W22, const float* __restrict__ W33,
        const float* __restrict__ dinv, __half* __restrict__ h2) {
    __shared__ float Wls[3][HID][OUTF];
    __shared__ __half cl[8][HID];
    int t = threadIdx.x;
    {
        const float4* w40 = reinterpret_cast<const float4*>(W11);
        const float4* w41 = reinterpret_cast<const float4*>(W22);
        const float4* w42 = reinterpret_cast<const float4*>(W33);
        float4* d0 = reinterpret_cast<float4*>(&Wls[0][0][0]);
        float4* d1 = reinterpret_cast<float4*>(&Wls[1][0][0]);
        float4* d2 = reinterpret_cast<float4*>(&Wls[2][0][0]);
#pragma unroll
        for (int j = 0; j < 2; ++j) {
            d0[t + j * 256] = w40[t + j * 256];
            d1[t + j * 256] = w41[t + j * 256];
            d2[t + j * 256] = w42[t + j * 256];
        }
    }
    int row0 = blockIdx.x * 8;
    ((u32*)cl)[t] = ((const u32*)(comb + (size_t)row0 * HID))[t];
    __syncthreads();

    int col = t & 31;
    int rr  = t >> 5;
    int row = row0 + rr;
    float a0 = 0.f, a1 = 0.f, a2 = 0.f;
    for (int k = 0; k < HID; ++k) {
        float cv = __half2float(cl[rr][k]);
        a0 = fmaf(cv, Wls[0][k][col], a0);
        a1 = fmaf(cv, Wls[1][k][col], a1);
        a2 = fmaf(cv, Wls[2][k][col], a2);
    }
    float d0 = dinv[row], d1 = dinv[NN + row], d2 = dinv[2 * NN + row];
    h2[(size_t)0 * NN * OUTF + (size_t)row * OUTF + col] = __float2half(a0 * d0);
    h2[(size_t)1 * NN * OUTF + (size_t)row * OUTF + col] = __float2half(a1 * d1);
    h2[(size_t)2 * NN * OUTF + (size_t)row * OUTF + col] = __float2half(a2 * d2);
}

// ---------------- layer-2 aggregation, BRANCH-MAJOR: partial sums to outp[br] ----------------
__global__ __launch_bounds__(256) void k_agg2p(
        const u32* __restrict__ csr, const u32* __restrict__ nodeinfo,
        const float* __restrict__ dinv,
        const __half* __restrict__ h2, float* __restrict__ outp) {
    int bid = blockIdx.x;
    int br  = bid / NBLK;
    int nb  = bid - br * NBLK;
    int t   = threadIdx.x;
    int f2  = t & 15;
    int eo  = (t >> 4) & 3;
    int sub = __builtin_amdgcn_readfirstlane(t >> 6);
    int n   = nb * 4 + sub;

    int i   = br * NN + n;
    u32 inf = nodeinfo[i];
    int cc  = (int)(inf & 1023u);
    int st  = (int)(inf >> 10);
    const __half2* h2b = (const __half2*)(h2 + (size_t)br * NN * OUTF);
    float ax = 0.f, ay = 0.f;
    int cm1 = cc - 1;
    for (int j = 0; j < cc; j += 16) {
        u32 ee[4]; __half2 vv[4];
#pragma unroll
        for (int u = 0; u < 4; ++u) {
            int jj = j + 4 * u + eo;
            ee[u] = csr[st + (jj < cm1 ? jj : cm1)];
            if (jj >= cc) ee[u] &= 0xffffu;
        }
#pragma unroll
        for (int u = 0; u < 4; ++u)
            vv[u] = h2b[(size_t)(ee[u] & 0xffff) * 16 + f2];
#pragma unroll
        for (int u = 0; u < 4; ++u) {
            float w = __half2float(__ushort_as_half((u16)(ee[u] >> 16)));
            float2 v = __half22float2(vv[u]);
            ax = fmaf(w, v.x, ax);
            ay = fmaf(w, v.y, ay);
        }
    }
    ax += __shfl_xor(ax, 16); ay += __shfl_xor(ay, 16);
    ax += __shfl_xor(ax, 32); ay += __shfl_xor(ay, 32);
    float d = dinv[i];
    float2 hs = __half22float2(h2b[(size_t)n * 16 + f2]);
    if (eo == 0)
        ((float2*)outp)[((size_t)br * NN + n) * 16 + f2] =
            make_float2(d * (ax + hs.x), d * (ay + hs.y));
}

// ---------------- final sum: out = outp0+outp1+outp2 + (b11+b22+b33) ----------------
__global__ __launch_bounds__(256) void k_sum(
        const float* __restrict__ outp,
        const float* __restrict__ b11, const float* __restrict__ b22, const float* __restrict__ b33,
        float* __restrict__ out) {
    int i = blockIdx.x * 256 + threadIdx.x;
    int f2 = i & 15;
    const float2* p = (const float2*)outp;
    float2 v0 = p[i];
    float2 v1 = p[(size_t)NN * 16 + i];
    float2 v2 = p[(size_t)2 * NN * 16 + i];
    float2 bA = ((const float2*)b11)[f2];
    float2 bB = ((const float2*)b22)[f2];
    float2 bC = ((const float2*)b33)[f2];
    ((float2*)out)[i] = make_float2(v0.x + v1.x + v2.x + bA.x + bB.x + bC.x,
                                    v0.y + v1.y + v2.y + bA.y + bB.y + bC.y);
}

// ---------------- launch ----------------
extern "C" void kernel_launch(void* const* d_in, const int* in_sizes, int n_in,
                              void* d_out, int out_size, void* d_ws, size_t ws_size,
                              hipStream_t stream) {
    const float* x1  = (const float*)d_in[0];
    const float* x2  = (const float*)d_in[1];
    const float* x3  = (const float*)d_in[2];
    const int*   ei1 = (const int*)d_in[3];
    const int*   ei2 = (const int*)d_in[4];
    const int*   ei3 = (const int*)d_in[5];
    const float* ew1 = (const float*)d_in[6];
    const float* ew2 = (const float*)d_in[7];
    const float* ew3 = (const float*)d_in[8];
    const float* W1  = (const float*)d_in[9];
    const float* W2  = (const float*)d_in[10];
    const float* W3  = (const float*)d_in[11];
    const float* b1  = (const float*)d_in[12];
    const float* b2  = (const float*)d_in[13];
    const float* b3  = (const float*)d_in[14];
    const float* fcw = (const float*)d_in[15];
    const float* fcb = (const float*)d_in[16];
    const float* W11 = (const float*)d_in[17];
    const float* W22 = (const float*)d_in[18];
    const float* W33 = (const float*)d_in[19];
    const float* b11 = (const float*)d_in[20];
    const float* b22 = (const float*)d_in[21];
    const float* b33 = (const float*)d_in[22];

    float* out = (float*)d_out;
    float* coef_out = out + (size_t)NN * OUTF;

    // workspace layout; outp aliases bucketed (dead after k_bucket)
    u64*   bucketed  = (u64*)d_ws;                           // 3E u64   19.2 MB
    float* outp      = (float*)d_ws;                         // 3N*32 f32 alias
    u32*   csr       = (u32*)(bucketed + 3 * EE);            // 3E u32    9.6 MB
    u32*   bin_total = csr + 3 * EE;                         // 588
    u32*   binstart  = bin_total + NBIN;                     // 592
    u32*   blockbase = binstart + NBIN + 4;                  // 1176*196
    float* dinv      = (float*)(blockbase + NCNT * NBKT);    // 3N
    u32*   nodeinfo  = (u32*)(dinv + TOTN);                  // 3N
    f16*   Wt        = (f16*)(nodeinfo + TOTN);              // 3*64*256
    __half* h        = (__half*)(Wt + 3 * HID * INF_);       // 3N*64    19.2 MB
    __half* comb     = h + (size_t)TOTN * HID;               // N*64      6.4 MB
    __half* h2       = comb + (size_t)NN * HID;              // 3N*32     9.6 MB
    __half* e        = h2 + (size_t)TOTN * OUTF;             // 3N*64    19.2 MB

    k_prep<<<dim3(4), 256, 0, stream>>>(W1, W2, W3, Wt, bin_total);
    k_cntgemm<<<dim3(NCNT * 3), 256, 0, stream>>>(ei1, ei2, ei3, bin_total, blockbase,
                                                  x1, x2, x3, Wt, h);
    k_scan<<<dim3(1), 256, 0, stream>>>(bin_total, binstart);
    k_scatter<<<dim3(NCNT), 256, 0, stream>>>(ei1, ei2, ei3, ew1, ew2, ew3,
                                              binstart, blockbase, bucketed);
    k_bucket<<<dim3(NBIN), 256, 0, stream>>>(bucketed, bin_total, binstart,
                                             nodeinfo, dinv, csr, h);

    k_agg1<<<dim3(3 * NBLK), 256, 0, stream>>>(csr, nodeinfo, dinv, b1, b2, b3, h, e);
    k_attn<<<dim3(NN / 8), 256, 0, stream>>>(e, fcw, fcb, comb, coef_out);
    k_gemm2<<<dim3(NN / 8), 256, 0, stream>>>(comb, W11, W22, W33, dinv, h2);
    k_agg2p<<<dim3(3 * NBLK), 256, 0, stream>>>(csr, nodeinfo, dinv, h2, outp);
    k_sum<<<dim3(3125), 256, 0, stream>>>(outp, b11, b22, b33, out);
}

// Round 13
// 292.177 us; speedup vs baseline: 1.0943x; 1.0943x over previous
//
#include <hip/hip_runtime.h>
#include <hip/hip_fp16.h>
#include <math.h>

#define NN    50000
#define INF_  256
#define HID   64
#define OUTF  32
#define EE    800000
#define TOTN  (3 * NN)
#define NBKT  196
#define NBIN  (3 * NBKT)     // 588
#define CBLK  392
#define NCNT  (3 * CBLK)     // 1176
#define GB    782
#define NGEMM (3 * GB)       // 2346
#define MAXB  5120
#define NBLK  12500

typedef unsigned long long u64;
typedef unsigned int       u32;
typedef unsigned short     u16;
typedef _Float16           f16;
typedef f16   f16x8 __attribute__((ext_vector_type(8)));
typedef f16   f16x4 __attribute__((ext_vector_type(4)));
typedef float f32x4 __attribute__((ext_vector_type(4)));

// ---------------- prep: zero bins + swizzle W -> fragment-major Wt2 ----------------
// Wt2[b][(c*8+kt)*64+lane][e] : B-frag for (c,kt) is a coalesced 1KB wave read.
__global__ __launch_bounds__(256) void k_prep(
        const float* __restrict__ W1, const float* __restrict__ W2, const float* __restrict__ W3,
        f16* __restrict__ Wt2, u32* __restrict__ bin_total) {
    int blk = blockIdx.x, t = threadIdx.x;
    if (blk == 3) {
        for (int i = t; i < NBIN; i += 256) bin_total[i] = 0;
        return;
    }
    const float* W = (blk == 0) ? W1 : (blk == 1) ? W2 : W3;
    f16* wt = Wt2 + blk * 16384;
    for (int idx = t; idx < 16384; idx += 256) {
        int e    = idx & 7;
        int lane = (idx >> 3) & 63;
        int kt   = (idx >> 9) & 7;
        int c    = idx >> 12;
        int col  = c * 16 + (lane & 15);
        int k    = kt * 32 + ((lane >> 4) << 3) + e;
        wt[idx] = (f16)W[k * HID + col];
    }
}

// ---------------- fused: bucket-count + single-barrier staged MFMA gemm, 2:1 ----------------
__global__ __launch_bounds__(256) void k_cntgemm(
        const int* __restrict__ ei1, const int* __restrict__ ei2, const int* __restrict__ ei3,
        u32* __restrict__ bin_total, u32* __restrict__ blockbase,
        const float* __restrict__ x1, const float* __restrict__ x2, const float* __restrict__ x3,
        const f16* __restrict__ Wt2, __half* __restrict__ h) {
    __shared__ f16 xl[64][264];     // 33 KB; row stride 528B = 33*16B
    int bid = blockIdx.x;
    int q = bid / 3, r = bid - q * 3;
    int t = threadIdx.x;

    if (r == 2) {                   // ---- count block: q in [0,1176) ----
        u32* bins = (u32*)xl;
        int cb  = q;
        int br  = cb / CBLK;
        int blk = cb - br * CBLK;
        const int* ei = (br == 0) ? ei1 : (br == 1) ? ei2 : ei3;
        for (int i = t; i < NBKT; i += 256) bins[i] = 0;
        __syncthreads();
        int e0 = blk * 2048;
#pragma unroll
        for (int k = 0; k < 8; ++k) {
            int e = e0 + k * 256 + t;
            if (e < EE) atomicAdd(&bins[(u32)ei[EE + e] >> 8], 1u);
        }
        __syncthreads();
        for (int i = t; i < NBKT; i += 256) {
            u32 c = bins[i];
            u32 base = atomicAdd(&bin_total[br * NBKT + i], c);
            blockbase[cb * NBKT + i] = base;
        }
        return;
    }

    // ---- gemm: gid in [0, NGEMM) ----
    int gid = q * 2 + r;
    if (gid >= NGEMM) return;
    int b = gid / GB;
    int row_base = (gid - b * GB) * 64;
    const float4* x4 = reinterpret_cast<const float4*>((b == 0) ? x1 : (b == 1) ? x2 : x3);
    const f16* wt2 = Wt2 + b * 16384;
    __half* hb = h + (size_t)b * NN * HID;

    // stage whole 64x256 x-tile: 16 thread-contiguous float4 loads (all in flight)
    float4 v[16];
#pragma unroll
    for (int j = 0; j < 16; ++j) {
        int flat = j * 256 + t;
        int gr = row_base + (flat >> 6);
        v[j] = (gr < NN) ? x4[(size_t)row_base * 64 + flat]
                         : make_float4(0.f, 0.f, 0.f, 0.f);
    }
#pragma unroll
    for (int j = 0; j < 16; ++j) {
        int flat = j * 256 + t;
        int rr = flat >> 6, c4 = flat & 63;
        f16x4 p = {(f16)v[j].x, (f16)v[j].y, (f16)v[j].z, (f16)v[j].w};
        *(f16x4*)&xl[rr][c4 * 4] = p;
    }
    __syncthreads();                 // the ONLY barrier in the gemm path

    int w    = t >> 6;
    int lane = t & 63;
    int lrow = lane & 15;
    int lk   = (lane >> 4) * 8;
    int arow = (w << 4) + lrow;

    f32x4 acc[4] = {{0,0,0,0},{0,0,0,0},{0,0,0,0},{0,0,0,0}};
#pragma unroll
    for (int kt = 0; kt < 8; ++kt) {
        f16x8 af = *(const f16x8*)&xl[arow][kt * 32 + lk];
#pragma unroll
        for (int c = 0; c < 4; ++c) {
            f16x8 bf = *(const f16x8*)&wt2[((c * 8 + kt) * 64 + lane) * 8];
            acc[c] = __builtin_amdgcn_mfma_f32_16x16x32_f16(af, bf, acc[c], 0, 0, 0);
        }
    }
    int orow0 = row_base + (w << 4) + ((lane >> 4) << 2);
#pragma unroll
    for (int c = 0; c < 4; ++c) {
#pragma unroll
        for (int i = 0; i < 4; ++i) {
            int row = orow0 + i;
            if (row < NN) hb[(size_t)row * HID + c * 16 + lrow] = __float2half(acc[c][i]);
        }
    }
}

// ---------------- parallel scan of 588 bucket totals ----------------
__global__ __launch_bounds__(256) void k_scan(const u32* __restrict__ bin_total,
                                              u32* __restrict__ binstart) {
    __shared__ u32 s[256];
    int t = threadIdx.x;
    u32 c[3]; u32 sum = 0;
#pragma unroll
    for (int k = 0; k < 3; ++k) {
        int i = t * 3 + k;
        c[k] = (i < NBIN) ? bin_total[i] : 0;
        sum += c[k];
    }
    s[t] = sum;
    __syncthreads();
    for (int d = 1; d < 256; d <<= 1) {
        u32 v = (t >= d) ? s[t - d] : 0;
        __syncthreads();
        s[t] += v;
        __syncthreads();
    }
    u32 run = s[t] - sum;
#pragma unroll
    for (int k = 0; k < 3; ++k) {
        int i = t * 3 + k;
        if (i < NBIN) binstart[i] = run;
        run += c[k];
    }
    if (t == 255) binstart[NBIN] = run;
}

// ---------------- scatter edges into bucket-contiguous regions ----------------
__global__ __launch_bounds__(256) void k_scatter(
        const int* __restrict__ ei1, const int* __restrict__ ei2, const int* __restrict__ ei3,
        const float* __restrict__ ew1, const float* __restrict__ ew2, const float* __restrict__ ew3,
        const u32* __restrict__ binstart, const u32* __restrict__ blockbase,
        u64* __restrict__ bucketed) {
    __shared__ u32 cur[NBKT];
    int cb  = blockIdx.x;
    int br  = cb / CBLK;
    int blk = cb - br * CBLK;
    const int*   ei = (br == 0) ? ei1 : (br == 1) ? ei2 : ei3;
    const float* ew = (br == 0) ? ew1 : (br == 1) ? ew2 : ew3;
    int t = threadIdx.x;
    for (int i = t; i < NBKT; i += 256) cur[i] = 0;
    __syncthreads();
    int e0 = blk * 2048;
#pragma unroll
    for (int k = 0; k < 8; ++k) {
        int e = e0 + k * 256 + t;
        if (e < EE) {
            u32 dst = (u32)ei[EE + e];
            u32 src = (u32)ei[e];
            u32 bkt = dst >> 8;
            u32 rnk = atomicAdd(&cur[bkt], 1u);
            u32 pos = binstart[br * NBKT + bkt] + blockbase[cb * NBKT + bkt] + rnk;
            bucketed[pos] = ((u64)__float_as_uint(ew[e]) << 32) | (src << 8) | (dst & 0xffu);
        }
    }
}

// ---------------- per-bucket: nodeinfo/dinv/CSR in LDS + h-prescale of owned rows ----------------
__global__ __launch_bounds__(256) void k_bucket(
        const u64* __restrict__ bucketed, const u32* __restrict__ bin_total,
        const u32* __restrict__ binstart,
        u32* __restrict__ nodeinfo, float* __restrict__ dinv,
        u32* __restrict__ csr, __half* __restrict__ h) {
    __shared__ u32   scnt[256];
    __shared__ float swsum[256];
    __shared__ u32   scur[256];
    __shared__ u32   sscan[256];
    __shared__ float sdiv[256];
    __shared__ u32   lcsr[MAXB];
    int bin = blockIdx.x;
    int br  = bin / NBKT;
    int bkt = bin - br * NBKT;
    int t = threadIdx.x;
    u32 base = binstart[bin];
    u32 ecnt = bin_total[bin];
    scnt[t] = 0; swsum[t] = 0.f; scur[t] = 0;
    __syncthreads();
    for (u32 i = t; i < ecnt; i += 256) {
        u64 e = bucketed[base + i];
        u32 dl = (u32)e & 0xffu;
        atomicAdd(&scnt[dl], 1u);
        atomicAdd(&swsum[dl], __uint_as_float((u32)(e >> 32)));
    }
    __syncthreads();
    sscan[t] = scnt[t];
    __syncthreads();
    for (int d = 1; d < 256; d <<= 1) {
        u32 v = (t >= d) ? sscan[t - d] : 0;
        __syncthreads();
        sscan[t] += v;
        __syncthreads();
    }
    u32 lstart = sscan[t] - scnt[t];
    float d = rsqrtf(1.0f + swsum[t]);
    sdiv[t] = d;
    int n = bkt * 256 + t;
    if (n < NN) {
        int gi = br * NN + n;
        nodeinfo[gi] = ((base + lstart) << 10) | scnt[t];
        dinv[gi]     = d;
    }
    __syncthreads();
    for (u32 i = t; i < ecnt; i += 256) {
        u64 e = bucketed[base + i];
        u32 dl  = (u32)e & 0xffu;
        u32 src = (u32)(e >> 8) & 0xffffu;
        float w = __uint_as_float((u32)(e >> 32));
        u32 rnk = atomicAdd(&scur[dl], 1u);
        u32 ls  = sscan[dl] - scnt[dl];
        lcsr[ls + rnk] = ((u32)__half_as_ushort(__float2half(w)) << 16) | src;
    }
    __syncthreads();
    for (u32 i = t; i < ecnt; i += 256) csr[base + i] = lcsr[i];

    int nrows = NN - bkt * 256; if (nrows > 256) nrows = 256;
    u32* hrow = (u32*)(h + ((size_t)br * NN + (size_t)bkt * 256) * HID);
    for (int i = t; i < nrows * 32; i += 256) {
        float dd = sdiv[i >> 5];
        __half2 hv = *(__half2*)&hrow[i];
        float2 v = __half22float2(hv);
        __half2 r = __float22half2_rn(make_float2(v.x * dd, v.y * dd));
        hrow[i] = *(u32*)&r;
    }
}

// ---------------- layer-1 aggregation, BRANCH-MAJOR: e = ReLU(...) ----------------
__global__ __launch_bounds__(256) void k_agg1(
        const u32* __restrict__ csr, const u32* __restrict__ nodeinfo,
        const float* __restrict__ dinv,
        const float* __restrict__ b1, const float* __restrict__ b2, const float* __restrict__ b3,
        const __half* __restrict__ h, __half* __restrict__ e) {
    int bid = blockIdx.x;
    int br  = bid / NBLK;
    int nb  = bid - br * NBLK;
    int t   = threadIdx.x;
    int f2  = t & 31;
    int eo  = (t >> 5) & 1;
    int sub = __builtin_amdgcn_readfirstlane(t >> 6);
    int n   = nb * 4 + sub;

    const float* bi = (br == 0) ? b1 : (br == 1) ? b2 : b3;
    const __half2* hb2 = (const __half2*)(h + (size_t)br * NN * HID);
    int i   = br * NN + n;
    u32 inf = nodeinfo[i];
    int cc  = (int)(inf & 1023u);
    int st  = (int)(inf >> 10);
    float d = dinv[i];
    float2 hs = __half22float2(hb2[(size_t)n * 32 + f2]);

    float ax = 0.f, ay = 0.f;
    int cm1 = cc - 1;
    for (int j = 0; j < cc; j += 16) {
        u32 ee[8]; __half2 vv[8];
#pragma unroll
        for (int u = 0; u < 8; ++u) {
            int jj = j + 2 * u + eo;
            ee[u] = csr[st + (jj < cm1 ? jj : cm1)];
            if (jj >= cc) ee[u] &= 0xffffu;
        }
#pragma unroll
        for (int u = 0; u < 8; ++u)
            vv[u] = hb2[(size_t)(ee[u] & 0xffff) * 32 + f2];
#pragma unroll
        for (int u = 0; u < 8; ++u) {
            float w = __half2float(__ushort_as_half((u16)(ee[u] >> 16)));
            float2 v = __half22float2(vv[u]);
            ax = fmaf(w, v.x, ax);
            ay = fmaf(w, v.y, ay);
        }
    }
    ax += __shfl_xor(ax, 32);
    ay += __shfl_xor(ay, 32);
    float2 bv = ((const float2*)bi)[f2];
    float ex = fmaxf(bv.x + d * (hs.x + ax), 0.f);
    float ey = fmaxf(bv.y + d * (hs.y + ay), 0.f);
    if (eo == 0)
        ((__half2*)e)[((size_t)br * NN + n) * 32 + f2] = __float22half2_rn(make_float2(ex, ey));
}

// ---------------- attention: coefs + comb from e ----------------
__global__ __launch_bounds__(256) void k_attn(
        const __half* __restrict__ e,
        const float* __restrict__ fc_w, const float* __restrict__ fc_b,
        __half* __restrict__ comb, float* __restrict__ coef_out) {
    int t    = threadIdx.x;
    int lane = t & 63;
    int sub  = __builtin_amdgcn_readfirstlane(t >> 6);
    int half = lane >> 5;
    int f2   = lane & 31;
    int n    = blockIdx.x * 8 + sub * 2 + half;
    float2 wv = ((const float2*)fc_w)[f2];
    float fb = fc_b[0];
    const __half2* e2 = (const __half2*)e;

    float2 ev[3]; float c[3];
#pragma unroll
    for (int b = 0; b < 3; ++b) {
        ev[b] = __half22float2(e2[((size_t)b * NN + n) * 32 + f2]);
        float dd = ev[b].x * wv.x + ev[b].y * wv.y;
#pragma unroll
        for (int off = 16; off > 0; off >>= 1) dd += __shfl_xor(dd, off);
        float z = dd + fb;
        z = (z > 0.f) ? z : 0.01f * z;
        c[b] = expf(z);
    }
    float cd = c[0] + c[1] + c[2];
    float coef0 = c[0] / cd, coef1 = c[1] / cd, coef2 = c[2] / cd;
    float cx = ev[0].x * coef0 + ev[1].x * coef1 + ev[2].x * coef2;
    float cy = ev[0].y * coef0 + ev[1].y * coef1 + ev[2].y * coef2;
    ((__half2*)comb)[(size_t)n * 32 + f2] = __float22half2_rn(make_float2(cx, cy));
    if (f2 == 0) {
        coef_out[n]          = coef0;
        coef_out[NN + n]     = coef1;
        coef_out[2 * NN + n] = coef2;
    }
}

// ---------------- layer-2 GEMM: h2'[b] = dinv * (comb @ W_b) ----------------
__global__ __launch_bounds__(256) void k_gemm2(
        const __half* __restrict__ comb,
        const float* __restrict__ W11, const float* __restrict__ W22, const float* __restrict__ W33,
        const float* __restrict__ dinv, __half* __restrict__ h2) {
    __shared__ float Wls[3][HID][OUTF];
    __shared__ __half cl[8][HID];
    int t = threadIdx.x;
    {
        const float4* w40 = reinterpret_cast<const float4*>(W11);
        const float4* w41 = reinterpret_cast<const float4*>(W22);
        const float4* w42 = reinterpret_cast<const float4*>(W33);
        float4* d0 = reinterpret_cast<float4*>(&Wls[0][0][0]);
        float4* d1 = reinterpret_cast<float4*>(&Wls[1][0][0]);
        float4* d2 = reinterpret_cast<float4*>(&Wls[2][0][0]);
#pragma unroll
        for (int j = 0; j < 2; ++j) {
            d0[t + j * 256] = w40[t + j * 256];
            d1[t + j * 256] = w41[t + j * 256];
            d2[t + j * 256] = w42[t + j * 256];
        }
    }
    int row0 = blockIdx.x * 8;
    ((u32*)cl)[t] = ((const u32*)(comb + (size_t)row0 * HID))[t];
    __syncthreads();

    int col = t & 31;
    int rr  = t >> 5;
    int row = row0 + rr;
    float a0 = 0.f, a1 = 0.f, a2 = 0.f;
    for (int k = 0; k < HID; ++k) {
        float cv = __half2float(cl[rr][k]);
        a0 = fmaf(cv, Wls[0][k][col], a0);
        a1 = fmaf(cv, Wls[1][k][col], a1);
        a2 = fmaf(cv, Wls[2][k][col], a2);
    }
    float d0 = dinv[row], d1 = dinv[NN + row], d2 = dinv[2 * NN + row];
    h2[(size_t)0 * NN * OUTF + (size_t)row * OUTF + col] = __float2half(a0 * d0);
    h2[(size_t)1 * NN * OUTF + (size_t)row * OUTF + col] = __float2half(a1 * d1);
    h2[(size_t)2 * NN * OUTF + (size_t)row * OUTF + col] = __float2half(a2 * d2);
}

// ---------------- layer-2 aggregation, BRANCH-MAJOR: partial sums ----------------
__global__ __launch_bounds__(256) void k_agg2p(
        const u32* __restrict__ csr, const u32* __restrict__ nodeinfo,
        const float* __restrict__ dinv,
        const __half* __restrict__ h2, float* __restrict__ outp) {
    int bid = blockIdx.x;
    int br  = bid / NBLK;
    int nb  = bid - br * NBLK;
    int t   = threadIdx.x;
    int f2  = t & 15;
    int eo  = (t >> 4) & 3;
    int sub = __builtin_amdgcn_readfirstlane(t >> 6);
    int n   = nb * 4 + sub;

    int i   = br * NN + n;
    u32 inf = nodeinfo[i];
    int cc  = (int)(inf & 1023u);
    int st  = (int)(inf >> 10);
    const __half2* h2b = (const __half2*)(h2 + (size_t)br * NN * OUTF);
    float ax = 0.f, ay = 0.f;
    int cm1 = cc - 1;
    for (int j = 0; j < cc; j += 16) {
        u32 ee[4]; __half2 vv[4];
#pragma unroll
        for (int u = 0; u < 4; ++u) {
            int jj = j + 4 * u + eo;
            ee[u] = csr[st + (jj < cm1 ? jj : cm1)];
            if (jj >= cc) ee[u] &= 0xffffu;
        }
#pragma unroll
        for (int u = 0; u < 4; ++u)
            vv[u] = h2b[(size_t)(ee[u] & 0xffff) * 16 + f2];
#pragma unroll
        for (int u = 0; u < 4; ++u) {
            float w = __half2float(__ushort_as_half((u16)(ee[u] >> 16)));
            float2 v = __half22float2(vv[u]);
            ax = fmaf(w, v.x, ax);
            ay = fmaf(w, v.y, ay);
        }
    }
    ax += __shfl_xor(ax, 16); ay += __shfl_xor(ay, 16);
    ax += __shfl_xor(ax, 32); ay += __shfl_xor(ay, 32);
    float d = dinv[i];
    float2 hs = __half22float2(h2b[(size_t)n * 16 + f2]);
    if (eo == 0)
        ((float2*)outp)[((size_t)br * NN + n) * 16 + f2] =
            make_float2(d * (ax + hs.x), d * (ay + hs.y));
}

// ---------------- final sum ----------------
__global__ __launch_bounds__(256) void k_sum(
        const float* __restrict__ outp,
        const float* __restrict__ b11, const float* __restrict__ b22, const float* __restrict__ b33,
        float* __restrict__ out) {
    int i = blockIdx.x * 256 + threadIdx.x;
    int f2 = i & 15;
    const float2* p = (const float2*)outp;
    float2 v0 = p[i];
    float2 v1 = p[(size_t)NN * 16 + i];
    float2 v2 = p[(size_t)2 * NN * 16 + i];
    float2 bA = ((const float2*)b11)[f2];
    float2 bB = ((const float2*)b22)[f2];
    float2 bC = ((const float2*)b33)[f2];
    ((float2*)out)[i] = make_float2(v0.x + v1.x + v2.x + bA.x + bB.x + bC.x,
                                    v0.y + v1.y + v2.y + bA.y + bB.y + bC.y);
}

// ---------------- launch ----------------
extern "C" void kernel_launch(void* const* d_in, const int* in_sizes, int n_in,
                              void* d_out, int out_size, void* d_ws, size_t ws_size,
                              hipStream_t stream) {
    const float* x1  = (const float*)d_in[0];
    const float* x2  = (const float*)d_in[1];
    const float* x3  = (const float*)d_in[2];
    const int*   ei1 = (const int*)d_in[3];
    const int*   ei2 = (const int*)d_in[4];
    const int*   ei3 = (const int*)d_in[5];
    const float* ew1 = (const float*)d_in[6];
    const float* ew2 = (const float*)d_in[7];
    const float* ew3 = (const float*)d_in[8];
    const float* W1  = (const float*)d_in[9];
    const float* W2  = (const float*)d_in[10];
    const float* W3  = (const float*)d_in[11];
    const float* b1  = (const float*)d_in[12];
    const float* b2  = (const float*)d_in[13];
    const float* b3  = (const float*)d_in[14];
    const float* fcw = (const float*)d_in[15];
    const float* fcb = (const float*)d_in[16];
    const float* W11 = (const float*)d_in[17];
    const float* W22 = (const float*)d_in[18];
    const float* W33 = (const float*)d_in[19];
    const float* b11 = (const float*)d_in[20];
    const float* b22 = (const float*)d_in[21];
    const float* b33 = (const float*)d_in[22];

    float* out = (float*)d_out;
    float* coef_out = out + (size_t)NN * OUTF;

    // workspace layout; outp aliases bucketed (dead after k_bucket)
    u64*   bucketed  = (u64*)d_ws;
    float* outp      = (float*)d_ws;
    u32*   csr       = (u32*)(bucketed + 3 * EE);
    u32*   bin_total = csr + 3 * EE;
    u32*   binstart  = bin_total + NBIN;
    u32*   blockbase = binstart + NBIN + 4;
    float* dinv      = (float*)(blockbase + NCNT * NBKT);
    u32*   nodeinfo  = (u32*)(dinv + TOTN);
    f16*   Wt2       = (f16*)(nodeinfo + TOTN);
    __half* h        = (__half*)(Wt2 + 3 * 16384);
    __half* comb     = h + (size_t)TOTN * HID;
    __half* h2       = comb + (size_t)NN * HID;
    __half* e        = h2 + (size_t)TOTN * OUTF;

    k_prep<<<dim3(4), 256, 0, stream>>>(W1, W2, W3, Wt2, bin_total);
    k_cntgemm<<<dim3(NCNT * 3), 256, 0, stream>>>(ei1, ei2, ei3, bin_total, blockbase,
                                                  x1, x2, x3, Wt2, h);
    k_scan<<<dim3(1), 256, 0, stream>>>(bin_total, binstart);
    k_scatter<<<dim3(NCNT), 256, 0, stream>>>(ei1, ei2, ei3, ew1, ew2, ew3,
                                              binstart, blockbase, bucketed);
    k_bucket<<<dim3(NBIN), 256, 0, stream>>>(bucketed, bin_total, binstart,
                                             nodeinfo, dinv, csr, h);

    k_agg1<<<dim3(3 * NBLK), 256, 0, stream>>>(csr, nodeinfo, dinv, b1, b2, b3, h, e);
    k_attn<<<dim3(NN / 8), 256, 0, stream>>>(e, fcw, fcb, comb, coef_out);
    k_gemm2<<<dim3(NN / 8), 256, 0, stream>>>(comb, W11, W22, W33, dinv, h2);
    k_agg2p<<<dim3(3 * NBLK), 256, 0, stream>>>(csr, nodeinfo, dinv, h2, outp);
    k_sum<<<dim3(3125), 256, 0, stream>>>(outp, b11, b22, b33, out);
}

// Round 14
// 286.460 us; speedup vs baseline: 1.1161x; 1.0200x over previous
//
#include <hip/hip_runtime.h>
#include <hip/hip_fp16.h>
#include <math.h>

#define NN    50000
#define INF_  256
#define HID   64
#define OUTF  32
#define EE    800000
#define TOTN  (3 * NN)
#define NBKT  196
#define NBIN  (3 * NBKT)     // 588
#define CBLK  392
#define NCNT  (3 * CBLK)     // 1176
#define GB    782
#define NGEMM (3 * GB)       // 2346
#define MAXB  5120
#define NBLK  12500

typedef unsigned long long u64;
typedef unsigned int       u32;
typedef unsigned short     u16;
typedef _Float16           f16;
typedef f16   f16x8 __attribute__((ext_vector_type(8)));
typedef f16   f16x4 __attribute__((ext_vector_type(4)));
typedef float f32x4 __attribute__((ext_vector_type(4)));

// ---------------- prep: zero bins + swizzle W -> fragment-major Wt2 ----------------
__global__ __launch_bounds__(256) void k_prep(
        const float* __restrict__ W1, const float* __restrict__ W2, const float* __restrict__ W3,
        f16* __restrict__ Wt2, u32* __restrict__ bin_total) {
    int blk = blockIdx.x, t = threadIdx.x;
    if (blk == 3) {
        for (int i = t; i < NBIN; i += 256) bin_total[i] = 0;
        return;
    }
    const float* W = (blk == 0) ? W1 : (blk == 1) ? W2 : W3;
    f16* wt = Wt2 + blk * 16384;
    for (int idx = t; idx < 16384; idx += 256) {
        int e    = idx & 7;
        int lane = (idx >> 3) & 63;
        int kt   = (idx >> 9) & 7;
        int c    = idx >> 12;
        int col  = c * 16 + (lane & 15);
        int k    = kt * 32 + ((lane >> 4) << 3) + e;
        wt[idx] = (f16)W[k * HID + col];
    }
}

// ---------------- standalone bucket-count (LDS hist, cheap) ----------------
__global__ __launch_bounds__(256) void k_count(
        const int* __restrict__ ei1, const int* __restrict__ ei2, const int* __restrict__ ei3,
        u32* __restrict__ bin_total, u32* __restrict__ blockbase) {
    __shared__ u32 bins[NBKT];
    int cb  = blockIdx.x;            // 0..1175
    int br  = cb / CBLK;
    int blk = cb - br * CBLK;
    const int* ei = (br == 0) ? ei1 : (br == 1) ? ei2 : ei3;
    int t = threadIdx.x;
    for (int i = t; i < NBKT; i += 256) bins[i] = 0;
    __syncthreads();
    int e0 = blk * 2048;
#pragma unroll
    for (int k = 0; k < 8; ++k) {
        int e = e0 + k * 256 + t;
        if (e < EE) atomicAdd(&bins[(u32)ei[EE + e] >> 8], 1u);
    }
    __syncthreads();
    for (int i = t; i < NBKT; i += 256) {
        u32 c = bins[i];
        u32 base = atomicAdd(&bin_total[br * NBKT + i], c);
        blockbase[cb * NBKT + i] = base;
    }
}

// ---------------- parallel scan of 588 bucket totals ----------------
__global__ __launch_bounds__(256) void k_scan(const u32* __restrict__ bin_total,
                                              u32* __restrict__ binstart) {
    __shared__ u32 s[256];
    int t = threadIdx.x;
    u32 c[3]; u32 sum = 0;
#pragma unroll
    for (int k = 0; k < 3; ++k) {
        int i = t * 3 + k;
        c[k] = (i < NBIN) ? bin_total[i] : 0;
        sum += c[k];
    }
    s[t] = sum;
    __syncthreads();
    for (int d = 1; d < 256; d <<= 1) {
        u32 v = (t >= d) ? s[t - d] : 0;
        __syncthreads();
        s[t] += v;
        __syncthreads();
    }
    u32 run = s[t] - sum;
#pragma unroll
    for (int k = 0; k < 3; ++k) {
        int i = t * 3 + k;
        if (i < NBIN) binstart[i] = run;
        run += c[k];
    }
    if (t == 255) binstart[NBIN] = run;
}

// ---------------- fused: edge-scatter + single-barrier staged MFMA gemm, 1:2 ----------------
// period 3: r==2 -> scatter chunk q in [0,1176); else gemm gid=2q+r.
// Heterogeneous co-residency (R7 recipe): gemm compute hides scatter's
// latency-bound scattered 8B writes.
__global__ __launch_bounds__(256) void k_scatgemm(
        const int* __restrict__ ei1, const int* __restrict__ ei2, const int* __restrict__ ei3,
        const float* __restrict__ ew1, const float* __restrict__ ew2, const float* __restrict__ ew3,
        const u32* __restrict__ binstart, const u32* __restrict__ blockbase,
        u64* __restrict__ bucketed,
        const float* __restrict__ x1, const float* __restrict__ x2, const float* __restrict__ x3,
        const f16* __restrict__ Wt2, __half* __restrict__ h) {
    __shared__ f16 xl[64][264];     // 33 KB; scatter blocks reuse as cur[]
    int bid = blockIdx.x;
    int q = bid / 3, r = bid - q * 3;
    int t = threadIdx.x;

    if (r == 2) {                   // ---- scatter chunk ----
        u32* cur = (u32*)xl;
        int cb  = q;
        int br  = cb / CBLK;
        int blk = cb - br * CBLK;
        const int*   ei = (br == 0) ? ei1 : (br == 1) ? ei2 : ei3;
        const float* ew = (br == 0) ? ew1 : (br == 1) ? ew2 : ew3;
        for (int i = t; i < NBKT; i += 256) cur[i] = 0;
        __syncthreads();
        int e0 = blk * 2048;
#pragma unroll
        for (int k = 0; k < 8; ++k) {
            int e = e0 + k * 256 + t;
            if (e < EE) {
                u32 dst = (u32)ei[EE + e];
                u32 src = (u32)ei[e];
                u32 bkt = dst >> 8;
                u32 rnk = atomicAdd(&cur[bkt], 1u);
                u32 pos = binstart[br * NBKT + bkt] + blockbase[cb * NBKT + bkt] + rnk;
                bucketed[pos] = ((u64)__float_as_uint(ew[e]) << 32) | (src << 8) | (dst & 0xffu);
            }
        }
        return;
    }

    // ---- gemm: gid in [0, NGEMM) ----
    int gid = q * 2 + r;
    if (gid >= NGEMM) return;
    int b = gid / GB;
    int row_base = (gid - b * GB) * 64;
    const float4* x4 = reinterpret_cast<const float4*>((b == 0) ? x1 : (b == 1) ? x2 : x3);
    const f16* wt2 = Wt2 + b * 16384;
    __half* hb = h + (size_t)b * NN * HID;

    float4 v[16];
#pragma unroll
    for (int j = 0; j < 16; ++j) {
        int flat = j * 256 + t;
        int gr = row_base + (flat >> 6);
        v[j] = (gr < NN) ? x4[(size_t)row_base * 64 + flat]
                         : make_float4(0.f, 0.f, 0.f, 0.f);
    }
#pragma unroll
    for (int j = 0; j < 16; ++j) {
        int flat = j * 256 + t;
        int rr = flat >> 6, c4 = flat & 63;
        f16x4 p = {(f16)v[j].x, (f16)v[j].y, (f16)v[j].z, (f16)v[j].w};
        *(f16x4*)&xl[rr][c4 * 4] = p;
    }
    __syncthreads();                 // only barrier in gemm path

    int w    = t >> 6;
    int lane = t & 63;
    int lrow = lane & 15;
    int lk   = (lane >> 4) * 8;
    int arow = (w << 4) + lrow;

    f32x4 acc[4] = {{0,0,0,0},{0,0,0,0},{0,0,0,0},{0,0,0,0}};
#pragma unroll
    for (int kt = 0; kt < 8; ++kt) {
        f16x8 af = *(const f16x8*)&xl[arow][kt * 32 + lk];
#pragma unroll
        for (int c = 0; c < 4; ++c) {
            f16x8 bf = *(const f16x8*)&wt2[((c * 8 + kt) * 64 + lane) * 8];
            acc[c] = __builtin_amdgcn_mfma_f32_16x16x32_f16(af, bf, acc[c], 0, 0, 0);
        }
    }
    int orow0 = row_base + (w << 4) + ((lane >> 4) << 2);
#pragma unroll
    for (int c = 0; c < 4; ++c) {
#pragma unroll
        for (int i = 0; i < 4; ++i) {
            int row = orow0 + i;
            if (row < NN) hb[(size_t)row * HID + c * 16 + lrow] = __float2half(acc[c][i]);
        }
    }
}

// ---------------- per-bucket: nodeinfo/dinv/CSR in LDS + h-prescale ----------------
__global__ __launch_bounds__(256) void k_bucket(
        const u64* __restrict__ bucketed, const u32* __restrict__ bin_total,
        const u32* __restrict__ binstart,
        u32* __restrict__ nodeinfo, float* __restrict__ dinv,
        u32* __restrict__ csr, __half* __restrict__ h) {
    __shared__ u32   scnt[256];
    __shared__ float swsum[256];
    __shared__ u32   scur[256];
    __shared__ u32   sscan[256];
    __shared__ float sdiv[256];
    __shared__ u32   lcsr[MAXB];
    int bin = blockIdx.x;
    int br  = bin / NBKT;
    int bkt = bin - br * NBKT;
    int t = threadIdx.x;
    u32 base = binstart[bin];
    u32 ecnt = bin_total[bin];
    scnt[t] = 0; swsum[t] = 0.f; scur[t] = 0;
    __syncthreads();
    for (u32 i = t; i < ecnt; i += 256) {
        u64 e = bucketed[base + i];
        u32 dl = (u32)e & 0xffu;
        atomicAdd(&scnt[dl], 1u);
        atomicAdd(&swsum[dl], __uint_as_float((u32)(e >> 32)));
    }
    __syncthreads();
    sscan[t] = scnt[t];
    __syncthreads();
    for (int d = 1; d < 256; d <<= 1) {
        u32 v = (t >= d) ? sscan[t - d] : 0;
        __syncthreads();
        sscan[t] += v;
        __syncthreads();
    }
    u32 lstart = sscan[t] - scnt[t];
    float d = rsqrtf(1.0f + swsum[t]);
    sdiv[t] = d;
    int n = bkt * 256 + t;
    if (n < NN) {
        int gi = br * NN + n;
        nodeinfo[gi] = ((base + lstart) << 10) | scnt[t];
        dinv[gi]     = d;
    }
    __syncthreads();
    for (u32 i = t; i < ecnt; i += 256) {
        u64 e = bucketed[base + i];
        u32 dl  = (u32)e & 0xffu;
        u32 src = (u32)(e >> 8) & 0xffffu;
        float w = __uint_as_float((u32)(e >> 32));
        u32 rnk = atomicAdd(&scur[dl], 1u);
        u32 ls  = sscan[dl] - scnt[dl];
        lcsr[ls + rnk] = ((u32)__half_as_ushort(__float2half(w)) << 16) | src;
    }
    __syncthreads();
    for (u32 i = t; i < ecnt; i += 256) csr[base + i] = lcsr[i];

    int nrows = NN - bkt * 256; if (nrows > 256) nrows = 256;
    u32* hrow = (u32*)(h + ((size_t)br * NN + (size_t)bkt * 256) * HID);
    for (int i = t; i < nrows * 32; i += 256) {
        float dd = sdiv[i >> 5];
        __half2 hv = *(__half2*)&hrow[i];
        float2 v = __half22float2(hv);
        __half2 r = __float22half2_rn(make_float2(v.x * dd, v.y * dd));
        hrow[i] = *(u32*)&r;
    }
}

// ---------------- layer-1 aggregation, BRANCH-MAJOR: e = ReLU(...) ----------------
__global__ __launch_bounds__(256) void k_agg1(
        const u32* __restrict__ csr, const u32* __restrict__ nodeinfo,
        const float* __restrict__ dinv,
        const float* __restrict__ b1, const float* __restrict__ b2, const float* __restrict__ b3,
        const __half* __restrict__ h, __half* __restrict__ e) {
    int bid = blockIdx.x;
    int br  = bid / NBLK;
    int nb  = bid - br * NBLK;
    int t   = threadIdx.x;
    int f2  = t & 31;
    int eo  = (t >> 5) & 1;
    int sub = __builtin_amdgcn_readfirstlane(t >> 6);
    int n   = nb * 4 + sub;

    const float* bi = (br == 0) ? b1 : (br == 1) ? b2 : b3;
    const __half2* hb2 = (const __half2*)(h + (size_t)br * NN * HID);
    int i   = br * NN + n;
    u32 inf = nodeinfo[i];
    int cc  = (int)(inf & 1023u);
    int st  = (int)(inf >> 10);
    float d = dinv[i];
    float2 hs = __half22float2(hb2[(size_t)n * 32 + f2]);

    float ax = 0.f, ay = 0.f;
    int cm1 = cc - 1;
    for (int j = 0; j < cc; j += 16) {
        u32 ee[8]; __half2 vv[8];
#pragma unroll
        for (int u = 0; u < 8; ++u) {
            int jj = j + 2 * u + eo;
            ee[u] = csr[st + (jj < cm1 ? jj : cm1)];
            if (jj >= cc) ee[u] &= 0xffffu;
        }
#pragma unroll
        for (int u = 0; u < 8; ++u)
            vv[u] = hb2[(size_t)(ee[u] & 0xffff) * 32 + f2];
#pragma unroll
        for (int u = 0; u < 8; ++u) {
            float w = __half2float(__ushort_as_half((u16)(ee[u] >> 16)));
            float2 v = __half22float2(vv[u]);
            ax = fmaf(w, v.x, ax);
            ay = fmaf(w, v.y, ay);
        }
    }
    ax += __shfl_xor(ax, 32);
    ay += __shfl_xor(ay, 32);
    float2 bv = ((const float2*)bi)[f2];
    float ex = fmaxf(bv.x + d * (hs.x + ax), 0.f);
    float ey = fmaxf(bv.y + d * (hs.y + ay), 0.f);
    if (eo == 0)
        ((__half2*)e)[((size_t)br * NN + n) * 32 + f2] = __float22half2_rn(make_float2(ex, ey));
}

// ---------------- attention: coefs + comb from e ----------------
__global__ __launch_bounds__(256) void k_attn(
        const __half* __restrict__ e,
        const float* __restrict__ fc_w, const float* __restrict__ fc_b,
        __half* __restrict__ comb, float* __restrict__ coef_out) {
    int t    = threadIdx.x;
    int lane = t & 63;
    int sub  = __builtin_amdgcn_readfirstlane(t >> 6);
    int half = lane >> 5;
    int f2   = lane & 31;
    int n    = blockIdx.x * 8 + sub * 2 + half;
    float2 wv = ((const float2*)fc_w)[f2];
    float fb = fc_b[0];
    const __half2* e2 = (const __half2*)e;

    float2 ev[3]; float c[3];
#pragma unroll
    for (int b = 0; b < 3; ++b) {
        ev[b] = __half22float2(e2[((size_t)b * NN + n) * 32 + f2]);
        float dd = ev[b].x * wv.x + ev[b].y * wv.y;
#pragma unroll
        for (int off = 16; off > 0; off >>= 1) dd += __shfl_xor(dd, off);
        float z = dd + fb;
        z = (z > 0.f) ? z : 0.01f * z;
        c[b] = expf(z);
    }
    float cd = c[0] + c[1] + c[2];
    float coef0 = c[0] / cd, coef1 = c[1] / cd, coef2 = c[2] / cd;
    float cx = ev[0].x * coef0 + ev[1].x * coef1 + ev[2].x * coef2;
    float cy = ev[0].y * coef0 + ev[1].y * coef1 + ev[2].y * coef2;
    ((__half2*)comb)[(size_t)n * 32 + f2] = __float22half2_rn(make_float2(cx, cy));
    if (f2 == 0) {
        coef_out[n]          = coef0;
        coef_out[NN + n]     = coef1;
        coef_out[2 * NN + n] = coef2;
    }
}

// ---------------- layer-2 GEMM: h2'[b] = dinv * (comb @ W_b) ----------------
__global__ __launch_bounds__(256) void k_gemm2(
        const __half* __restrict__ comb,
        const float* __restrict__ W11, const float* __restrict__ W22, const float* __restrict__ W33,
        const float* __restrict__ dinv, __half* __restrict__ h2) {
    __shared__ float Wls[3][HID][OUTF];
    __shared__ __half cl[8][HID];
    int t = threadIdx.x;
    {
        const float4* w40 = reinterpret_cast<const float4*>(W11);
        const float4* w41 = reinterpret_cast<const float4*>(W22);
        const float4* w42 = reinterpret_cast<const float4*>(W33);
        float4* d0 = reinterpret_cast<float4*>(&Wls[0][0][0]);
        float4* d1 = reinterpret_cast<float4*>(&Wls[1][0][0]);
        float4* d2 = reinterpret_cast<float4*>(&Wls[2][0][0]);
#pragma unroll
        for (int j = 0; j < 2; ++j) {
            d0[t + j * 256] = w40[t + j * 256];
            d1[t + j * 256] = w41[t + j * 256];
            d2[t + j * 256] = w42[t + j * 256];
        }
    }
    int row0 = blockIdx.x * 8;
    ((u32*)cl)[t] = ((const u32*)(comb + (size_t)row0 * HID))[t];
    __syncthreads();

    int col = t & 31;
    int rr  = t >> 5;
    int row = row0 + rr;
    float a0 = 0.f, a1 = 0.f, a2 = 0.f;
    for (int k = 0; k < HID; ++k) {
        float cv = __half2float(cl[rr][k]);
        a0 = fmaf(cv, Wls[0][k][col], a0);
        a1 = fmaf(cv, Wls[1][k][col], a1);
        a2 = fmaf(cv, Wls[2][k][col], a2);
    }
    float d0 = dinv[row], d1 = dinv[NN + row], d2 = dinv[2 * NN + row];
    h2[(size_t)0 * NN * OUTF + (size_t)row * OUTF + col] = __float2half(a0 * d0);
    h2[(size_t)1 * NN * OUTF + (size_t)row * OUTF + col] = __float2half(a1 * d1);
    h2[(size_t)2 * NN * OUTF + (size_t)row * OUTF + col] = __float2half(a2 * d2);
}

// ---------------- layer-2 aggregation, BRANCH-MAJOR: partial sums ----------------
__global__ __launch_bounds__(256) void k_agg2p(
        const u32* __restrict__ csr, const u32* __restrict__ nodeinfo,
        const float* __restrict__ dinv,
        const __half* __restrict__ h2, float* __restrict__ outp) {
    int bid = blockIdx.x;
    int br  = bid / NBLK;
    int nb  = bid - br * NBLK;
    int t   = threadIdx.x;
    int f2  = t & 15;
    int eo  = (t >> 4) & 3;
    int sub = __builtin_amdgcn_readfirstlane(t >> 6);
    int n   = nb * 4 + sub;

    int i   = br * NN + n;
    u32 inf = nodeinfo[i];
    int cc  = (int)(inf & 1023u);
    int st  = (int)(inf >> 10);
    const __half2* h2b = (const __half2*)(h2 + (size_t)br * NN * OUTF);
    float ax = 0.f, ay = 0.f;
    int cm1 = cc - 1;
    for (int j = 0; j < cc; j += 16) {
        u32 ee[4]; __half2 vv[4];
#pragma unroll
        for (int u = 0; u < 4; ++u) {
            int jj = j + 4 * u + eo;
            ee[u] = csr[st + (jj < cm1 ? jj : cm1)];
            if (jj >= cc) ee[u] &= 0xffffu;
        }
#pragma unroll
        for (int u = 0; u < 4; ++u)
            vv[u] = h2b[(size_t)(ee[u] & 0xffff) * 16 + f2];
#pragma unroll
        for (int u = 0; u < 4; ++u) {
            float w = __half2float(__ushort_as_half((u16)(ee[u] >> 16)));
            float2 v = __half22float2(vv[u]);
            ax = fmaf(w, v.x, ax);
            ay = fmaf(w, v.y, ay);
        }
    }
    ax += __shfl_xor(ax, 16); ay += __shfl_xor(ay, 16);
    ax += __shfl_xor(ax, 32); ay += __shfl_xor(ay, 32);
    float d = dinv[i];
    float2 hs = __half22float2(h2b[(size_t)n * 16 + f2]);
    if (eo == 0)
        ((float2*)outp)[((size_t)br * NN + n) * 16 + f2] =
            make_float2(d * (ax + hs.x), d * (ay + hs.y));
}

// ---------------- final sum ----------------
__global__ __launch_bounds__(256) void k_sum(
        const float* __restrict__ outp,
        const float* __restrict__ b11, const float* __restrict__ b22, const float* __restrict__ b33,
        float* __restrict__ out) {
    int i = blockIdx.x * 256 + threadIdx.x;
    int f2 = i & 15;
    const float2* p = (const float2*)outp;
    float2 v0 = p[i];
    float2 v1 = p[(size_t)NN * 16 + i];
    float2 v2 = p[(size_t)2 * NN * 16 + i];
    float2 bA = ((const float2*)b11)[f2];
    float2 bB = ((const float2*)b22)[f2];
    float2 bC = ((const float2*)b33)[f2];
    ((float2*)out)[i] = make_float2(v0.x + v1.x + v2.x + bA.x + bB.x + bC.x,
                                    v0.y + v1.y + v2.y + bA.y + bB.y + bC.y);
}

// ---------------- launch ----------------
extern "C" void kernel_launch(void* const* d_in, const int* in_sizes, int n_in,
                              void* d_out, int out_size, void* d_ws, size_t ws_size,
                              hipStream_t stream) {
    const float* x1  = (const float*)d_in[0];
    const float* x2  = (const float*)d_in[1];
    const float* x3  = (const float*)d_in[2];
    const int*   ei1 = (const int*)d_in[3];
    const int*   ei2 = (const int*)d_in[4];
    const int*   ei3 = (const int*)d_in[5];
    const float* ew1 = (const float*)d_in[6];
    const float* ew2 = (const float*)d_in[7];
    const float* ew3 = (const float*)d_in[8];
    const float* W1  = (const float*)d_in[9];
    const float* W2  = (const float*)d_in[10];
    const float* W3  = (const float*)d_in[11];
    const float* b1  = (const float*)d_in[12];
    const float* b2  = (const float*)d_in[13];
    const float* b3  = (const float*)d_in[14];
    const float* fcw = (const float*)d_in[15];
    const float* fcb = (const float*)d_in[16];
    const float* W11 = (const float*)d_in[17];
    const float* W22 = (const float*)d_in[18];
    const float* W33 = (const float*)d_in[19];
    const float* b11 = (const float*)d_in[20];
    const float* b22 = (const float*)d_in[21];
    const float* b33 = (const float*)d_in[22];

    float* out = (float*)d_out;
    float* coef_out = out + (size_t)NN * OUTF;

    // workspace layout; outp aliases bucketed (dead after k_bucket)
    u64*   bucketed  = (u64*)d_ws;
    float* outp      = (float*)d_ws;
    u32*   csr       = (u32*)(bucketed + 3 * EE);
    u32*   bin_total = csr + 3 * EE;
    u32*   binstart  = bin_total + NBIN;
    u32*   blockbase = binstart + NBIN + 4;
    float* dinv      = (float*)(blockbase + NCNT * NBKT);
    u32*   nodeinfo  = (u32*)(dinv + TOTN);
    f16*   Wt2       = (f16*)(nodeinfo + TOTN);
    __half* h        = (__half*)(Wt2 + 3 * 16384);
    __half* comb     = h + (size_t)TOTN * HID;
    __half* h2       = comb + (size_t)NN * HID;
    __half* e        = h2 + (size_t)TOTN * OUTF;

    k_prep<<<dim3(4), 256, 0, stream>>>(W1, W2, W3, Wt2, bin_total);
    k_count<<<dim3(NCNT), 256, 0, stream>>>(ei1, ei2, ei3, bin_total, blockbase);
    k_scan<<<dim3(1), 256, 0, stream>>>(bin_total, binstart);
    k_scatgemm<<<dim3(NCNT * 3), 256, 0, stream>>>(ei1, ei2, ei3, ew1, ew2, ew3,
                                                   binstart, blockbase, bucketed,
                                                   x1, x2, x3, Wt2, h);
    k_bucket<<<dim3(NBIN), 256, 0, stream>>>(bucketed, bin_total, binstart,
                                             nodeinfo, dinv, csr, h);

    k_agg1<<<dim3(3 * NBLK), 256, 0, stream>>>(csr, nodeinfo, dinv, b1, b2, b3, h, e);
    k_attn<<<dim3(NN / 8), 256, 0, stream>>>(e, fcw, fcb, comb, coef_out);
    k_gemm2<<<dim3(NN / 8), 256, 0, stream>>>(comb, W11, W22, W33, dinv, h2);
    k_agg2p<<<dim3(3 * NBLK), 256, 0, stream>>>(csr, nodeinfo, dinv, h2, outp);
    k_sum<<<dim3(3125), 256, 0, stream>>>(outp, b11, b22, b33, out);
}

// Round 15
// 272.497 us; speedup vs baseline: 1.1733x; 1.0512x over previous
//
#include <hip/hip_runtime.h>
#include <hip/hip_fp16.h>
#include <math.h>

#define NN    50000
#define INF_  256
#define HID   64
#define OUTF  32
#define EE    800000
#define TOTN  (3 * NN)
#define NBKT  196
#define NBIN  (3 * NBKT)     // 588
#define CBLK  196            // count/scatter chunks per branch (4096 edges each)
#define NCNT  (3 * CBLK)     // 588
#define GB    782
#define NGEMM (3 * GB)       // 2346
#define MAXB  5120
#define NBLK  12500

typedef unsigned long long u64;
typedef unsigned int       u32;
typedef unsigned short     u16;
typedef unsigned char      u8;
typedef _Float16           f16;
typedef f16   f16x8 __attribute__((ext_vector_type(8)));
typedef f16   f16x4 __attribute__((ext_vector_type(4)));
typedef float f32x4 __attribute__((ext_vector_type(4)));

// ---------------- prep: zero bins + swizzle W -> fragment-major Wt2 ----------------
__global__ __launch_bounds__(256) void k_prep(
        const float* __restrict__ W1, const float* __restrict__ W2, const float* __restrict__ W3,
        f16* __restrict__ Wt2, u32* __restrict__ bin_total) {
    int blk = blockIdx.x, t = threadIdx.x;
    if (blk == 3) {
        for (int i = t; i < NBIN; i += 256) bin_total[i] = 0;
        return;
    }
    const float* W = (blk == 0) ? W1 : (blk == 1) ? W2 : W3;
    f16* wt = Wt2 + blk * 16384;
    for (int idx = t; idx < 16384; idx += 256) {
        int e    = idx & 7;
        int lane = (idx >> 3) & 63;
        int kt   = (idx >> 9) & 7;
        int c    = idx >> 12;
        int col  = c * 16 + (lane & 15);
        int k    = kt * 32 + ((lane >> 4) << 3) + e;
        wt[idx] = (f16)W[k * HID + col];
    }
}

// ---------------- standalone bucket-count (LDS hist, 4096-edge chunks) ----------------
__global__ __launch_bounds__(256) void k_count(
        const int* __restrict__ ei1, const int* __restrict__ ei2, const int* __restrict__ ei3,
        u32* __restrict__ bin_total, u32* __restrict__ blockbase) {
    __shared__ u32 bins[NBKT];
    int cb  = blockIdx.x;            // 0..587
    int br  = cb / CBLK;
    int blk = cb - br * CBLK;
    const int* ei = (br == 0) ? ei1 : (br == 1) ? ei2 : ei3;
    int t = threadIdx.x;
    for (int i = t; i < NBKT; i += 256) bins[i] = 0;
    __syncthreads();
    int e0 = blk * 4096;
#pragma unroll
    for (int k = 0; k < 16; ++k) {
        int e = e0 + k * 256 + t;
        if (e < EE) atomicAdd(&bins[(u32)ei[EE + e] >> 8], 1u);
    }
    __syncthreads();
    for (int i = t; i < NBKT; i += 256) {
        u32 c = bins[i];
        u32 base = atomicAdd(&bin_total[br * NBKT + i], c);
        blockbase[cb * NBKT + i] = base;
    }
}

// ---------------- parallel scan of 588 bucket totals ----------------
__global__ __launch_bounds__(256) void k_scan(const u32* __restrict__ bin_total,
                                              u32* __restrict__ binstart) {
    __shared__ u32 s[256];
    int t = threadIdx.x;
    u32 c[3]; u32 sum = 0;
#pragma unroll
    for (int k = 0; k < 3; ++k) {
        int i = t * 3 + k;
        c[k] = (i < NBIN) ? bin_total[i] : 0;
        sum += c[k];
    }
    s[t] = sum;
    __syncthreads();
    for (int d = 1; d < 256; d <<= 1) {
        u32 v = (t >= d) ? s[t - d] : 0;
        __syncthreads();
        s[t] += v;
        __syncthreads();
    }
    u32 run = s[t] - sum;
#pragma unroll
    for (int k = 0; k < 3; ++k) {
        int i = t * 3 + k;
        if (i < NBIN) binstart[i] = run;
        run += c[k];
    }
    if (t == 255) binstart[NBIN] = run;
}

// ---------------- fused: LDS-reordered scatter + single-barrier staged MFMA gemm ----------------
// period 5: r==4 -> scatter chunk q in [0,588); else gemm gid=q*4+r.
// Scatter: hist -> scan -> LDS reorder (bucket-order) -> LINEAR write-out so
// consecutive lanes hit consecutive addresses within each bucket run.
__global__ __launch_bounds__(256) void k_scatgemm(
        const int* __restrict__ ei1, const int* __restrict__ ei2, const int* __restrict__ ei3,
        const float* __restrict__ ew1, const float* __restrict__ ew2, const float* __restrict__ ew3,
        const u32* __restrict__ binstart, const u32* __restrict__ blockbase,
        u64* __restrict__ bucketed,
        const float* __restrict__ x1, const float* __restrict__ x2, const float* __restrict__ x3,
        const f16* __restrict__ Wt2, __half* __restrict__ h) {
    __shared__ __align__(16) char smem[36864];   // 36 KB -> 4 blocks/CU
    int bid = blockIdx.x;
    int q = bid / 5, r = bid - q * 5;
    int t = threadIdx.x;

    if (r == 4) {                   // ---- scatter chunk (q in [0,588)) ----
        u64* ent  = (u64*)smem;                    // 4096 x 8B = 32 KB
        u32* acnt = (u32*)(smem + 32768);          // 256
        u32* ascn = acnt + 256;                    // 256
        u32* acur = ascn + 256;                    // 256
        u32* adel = acur + 256;                    // 256
        int cb  = q;
        int br  = cb / CBLK;
        int blk = cb - br * CBLK;
        const int*   ei = (br == 0) ? ei1 : (br == 1) ? ei2 : ei3;
        const float* ew = (br == 0) ? ew1 : (br == 1) ? ew2 : ew3;
        acnt[t] = 0; acur[t] = 0;
        __syncthreads();
        int e0 = blk * 4096;
        int tot = EE - e0; if (tot > 4096) tot = 4096;
        // pass 1: histogram
#pragma unroll
        for (int k = 0; k < 16; ++k) {
            int e = e0 + k * 256 + t;
            if (e < EE) atomicAdd(&acnt[(u32)ei[EE + e] >> 8], 1u);
        }
        __syncthreads();
        // inclusive scan of acnt -> ascn
        ascn[t] = acnt[t];
        __syncthreads();
        for (int d = 1; d < 256; d <<= 1) {
            u32 v = (t >= d) ? ascn[t - d] : 0;
            __syncthreads();
            ascn[t] += v;
            __syncthreads();
        }
        // delta[bkt] = global_base - local_start  (u32 wraparound ok)
        if (t < NBKT)
            adel[t] = binstart[br * NBKT + t] + blockbase[cb * NBKT + t]
                      - (ascn[t] - acnt[t]);
        __syncthreads();
        // pass 2: re-read edges (L1/L2-hot), reorder into LDS in bucket order
#pragma unroll
        for (int k = 0; k < 16; ++k) {
            int e = e0 + k * 256 + t;
            if (e < EE) {
                u32 dst = (u32)ei[EE + e];
                u32 src = (u32)ei[e];
                u32 bkt = dst >> 8;
                u16 w16 = __half_as_ushort(__float2half(ew[e]));
                u32 rnk = atomicAdd(&acur[bkt], 1u);
                u32 ls  = ascn[bkt] - acnt[bkt] + rnk;
                ent[ls] = ((u64)bkt << 48) | ((u64)w16 << 32)
                        | ((u64)src << 8) | (u64)(dst & 0xffu);
            }
        }
        __syncthreads();
        // linear write-out: consecutive threads -> consecutive slots -> coalesced runs
        for (int i = t; i < tot; i += 256) {
            u64 ev = ent[i];
            u32 bkt = (u32)(ev >> 48) & 0xffu;
            bucketed[adel[bkt] + i] = ev;
        }
        return;
    }

    // ---- gemm: gid in [0, NGEMM) ----
    int gid = q * 4 + r;
    if (gid >= NGEMM) return;
    f16 (*xl)[264] = reinterpret_cast<f16(*)[264]>(smem);   // 33792 B
    int b = gid / GB;
    int row_base = (gid - b * GB) * 64;
    const float4* x4 = reinterpret_cast<const float4*>((b == 0) ? x1 : (b == 1) ? x2 : x3);
    const f16* wt2 = Wt2 + b * 16384;
    __half* hb = h + (size_t)b * NN * HID;

    float4 v[16];
#pragma unroll
    for (int j = 0; j < 16; ++j) {
        int flat = j * 256 + t;
        int gr = row_base + (flat >> 6);
        v[j] = (gr < NN) ? x4[(size_t)row_base * 64 + flat]
                         : make_float4(0.f, 0.f, 0.f, 0.f);
    }
#pragma unroll
    for (int j = 0; j < 16; ++j) {
        int flat = j * 256 + t;
        int rr = flat >> 6, c4 = flat & 63;
        f16x4 p = {(f16)v[j].x, (f16)v[j].y, (f16)v[j].z, (f16)v[j].w};
        *(f16x4*)&xl[rr][c4 * 4] = p;
    }
    __syncthreads();                 // only barrier in gemm path

    int w    = t >> 6;
    int lane = t & 63;
    int lrow = lane & 15;
    int lk   = (lane >> 4) * 8;
    int arow = (w << 4) + lrow;

    f32x4 acc[4] = {{0,0,0,0},{0,0,0,0},{0,0,0,0},{0,0,0,0}};
#pragma unroll
    for (int kt = 0; kt < 8; ++kt) {
        f16x8 af = *(const f16x8*)&xl[arow][kt * 32 + lk];
#pragma unroll
        for (int c = 0; c < 4; ++c) {
            f16x8 bf = *(const f16x8*)&wt2[((c * 8 + kt) * 64 + lane) * 8];
            acc[c] = __builtin_amdgcn_mfma_f32_16x16x32_f16(af, bf, acc[c], 0, 0, 0);
        }
    }
    int orow0 = row_base + (w << 4) + ((lane >> 4) << 2);
#pragma unroll
    for (int c = 0; c < 4; ++c) {
#pragma unroll
        for (int i = 0; i < 4; ++i) {
            int row = orow0 + i;
            if (row < NN) hb[(size_t)row * HID + c * 16 + lrow] = __float2half(acc[c][i]);
        }
    }
}

// ---------------- per-bucket: nodeinfo/dinv/CSR in LDS + h-prescale ----------------
__global__ __launch_bounds__(256) void k_bucket(
        const u64* __restrict__ bucketed, const u32* __restrict__ bin_total,
        const u32* __restrict__ binstart,
        u32* __restrict__ nodeinfo, float* __restrict__ dinv,
        u32* __restrict__ csr, __half* __restrict__ h) {
    __shared__ u32   scnt[256];
    __shared__ float swsum[256];
    __shared__ u32   scur[256];
    __shared__ u32   sscan[256];
    __shared__ float sdiv[256];
    __shared__ u32   lcsr[MAXB];
    int bin = blockIdx.x;
    int br  = bin / NBKT;
    int bkt = bin - br * NBKT;
    int t = threadIdx.x;
    u32 base = binstart[bin];
    u32 ecnt = bin_total[bin];
    scnt[t] = 0; swsum[t] = 0.f; scur[t] = 0;
    __syncthreads();
    for (u32 i = t; i < ecnt; i += 256) {
        u64 e = bucketed[base + i];
        u32 dl = (u32)e & 0xffu;
        atomicAdd(&scnt[dl], 1u);
        atomicAdd(&swsum[dl], __half2float(__ushort_as_half((u16)((e >> 32) & 0xffffu))));
    }
    __syncthreads();
    sscan[t] = scnt[t];
    __syncthreads();
    for (int d = 1; d < 256; d <<= 1) {
        u32 v = (t >= d) ? sscan[t - d] : 0;
        __syncthreads();
        sscan[t] += v;
        __syncthreads();
    }
    u32 lstart = sscan[t] - scnt[t];
    float d = rsqrtf(1.0f + swsum[t]);
    sdiv[t] = d;
    int n = bkt * 256 + t;
    if (n < NN) {
        int gi = br * NN + n;
        nodeinfo[gi] = ((base + lstart) << 10) | scnt[t];
        dinv[gi]     = d;
    }
    __syncthreads();
    for (u32 i = t; i < ecnt; i += 256) {
        u64 e = bucketed[base + i];
        u32 dl  = (u32)e & 0xffu;
        u32 src = (u32)(e >> 8) & 0xffffu;
        u32 w16 = (u32)(e >> 32) & 0xffffu;
        u32 rnk = atomicAdd(&scur[dl], 1u);
        u32 ls  = sscan[dl] - scnt[dl];
        lcsr[ls + rnk] = (w16 << 16) | src;
    }
    __syncthreads();
    for (u32 i = t; i < ecnt; i += 256) csr[base + i] = lcsr[i];

    int nrows = NN - bkt * 256; if (nrows > 256) nrows = 256;
    u32* hrow = (u32*)(h + ((size_t)br * NN + (size_t)bkt * 256) * HID);
    for (int i = t; i < nrows * 32; i += 256) {
        float dd = sdiv[i >> 5];
        __half2 hv = *(__half2*)&hrow[i];
        float2 v = __half22float2(hv);
        __half2 rr = __float22half2_rn(make_float2(v.x * dd, v.y * dd));
        hrow[i] = *(u32*)&rr;
    }
}

// ---------------- layer-1 aggregation, BRANCH-MAJOR: e = ReLU(...) ----------------
__global__ __launch_bounds__(256) void k_agg1(
        const u32* __restrict__ csr, const u32* __restrict__ nodeinfo,
        const float* __restrict__ dinv,
        const float* __restrict__ b1, const float* __restrict__ b2, const float* __restrict__ b3,
        const __half* __restrict__ h, __half* __restrict__ e) {
    int bid = blockIdx.x;
    int br  = bid / NBLK;
    int nb  = bid - br * NBLK;
    int t   = threadIdx.x;
    int f2  = t & 31;
    int eo  = (t >> 5) & 1;
    int sub = __builtin_amdgcn_readfirstlane(t >> 6);
    int n   = nb * 4 + sub;

    const float* bi = (br == 0) ? b1 : (br == 1) ? b2 : b3;
    const __half2* hb2 = (const __half2*)(h + (size_t)br * NN * HID);
    int i   = br * NN + n;
    u32 inf = nodeinfo[i];
    int cc  = (int)(inf & 1023u);
    int st  = (int)(inf >> 10);
    float d = dinv[i];
    float2 hs = __half22float2(hb2[(size_t)n * 32 + f2]);

    float ax = 0.f, ay = 0.f;
    int cm1 = cc - 1;
    for (int j = 0; j < cc; j += 16) {
        u32 ee[8]; __half2 vv[8];
#pragma unroll
        for (int u = 0; u < 8; ++u) {
            int jj = j + 2 * u + eo;
            ee[u] = csr[st + (jj < cm1 ? jj : cm1)];
            if (jj >= cc) ee[u] &= 0xffffu;
        }
#pragma unroll
        for (int u = 0; u < 8; ++u)
            vv[u] = hb2[(size_t)(ee[u] & 0xffff) * 32 + f2];
#pragma unroll
        for (int u = 0; u < 8; ++u) {
            float w = __half2float(__ushort_as_half((u16)(ee[u] >> 16)));
            float2 v = __half22float2(vv[u]);
            ax = fmaf(w, v.x, ax);
            ay = fmaf(w, v.y, ay);
        }
    }
    ax += __shfl_xor(ax, 32);
    ay += __shfl_xor(ay, 32);
    float2 bv = ((const float2*)bi)[f2];
    float ex = fmaxf(bv.x + d * (hs.x + ax), 0.f);
    float ey = fmaxf(bv.y + d * (hs.y + ay), 0.f);
    if (eo == 0)
        ((__half2*)e)[((size_t)br * NN + n) * 32 + f2] = __float22half2_rn(make_float2(ex, ey));
}

// ---------------- attention: coefs + comb from e ----------------
__global__ __launch_bounds__(256) void k_attn(
        const __half* __restrict__ e,
        const float* __restrict__ fc_w, const float* __restrict__ fc_b,
        __half* __restrict__ comb, float* __restrict__ coef_out) {
    int t    = threadIdx.x;
    int lane = t & 63;
    int sub  = __builtin_amdgcn_readfirstlane(t >> 6);
    int half = lane >> 5;
    int f2   = lane & 31;
    int n    = blockIdx.x * 8 + sub * 2 + half;
    float2 wv = ((const float2*)fc_w)[f2];
    float fb = fc_b[0];
    const __half2* e2 = (const __half2*)e;

    float2 ev[3]; float c[3];
#pragma unroll
    for (int b = 0; b < 3; ++b) {
        ev[b] = __half22float2(e2[((size_t)b * NN + n) * 32 + f2]);
        float dd = ev[b].x * wv.x + ev[b].y * wv.y;
#pragma unroll
        for (int off = 16; off > 0; off >>= 1) dd += __shfl_xor(dd, off);
        float z = dd + fb;
        z = (z > 0.f) ? z : 0.01f * z;
        c[b] = expf(z);
    }
    float cd = c[0] + c[1] + c[2];
    float coef0 = c[0] / cd, coef1 = c[1] / cd, coef2 = c[2] / cd;
    float cx = ev[0].x * coef0 + ev[1].x * coef1 + ev[2].x * coef2;
    float cy = ev[0].y * coef0 + ev[1].y * coef1 + ev[2].y * coef2;
    ((__half2*)comb)[(size_t)n * 32 + f2] = __float22half2_rn(make_float2(cx, cy));
    if (f2 == 0) {
        coef_out[n]          = coef0;
        coef_out[NN + n]     = coef1;
        coef_out[2 * NN + n] = coef2;
    }
}

// ---------------- layer-2 GEMM: h2'[b] = dinv * (comb @ W_b) ----------------
__global__ __launch_bounds__(256) void k_gemm2(
        const __half* __restrict__ comb,
        const float* __restrict__ W11, const float* __restrict__ W22, const float* __restrict__ W33,
        const float* __restrict__ dinv, __half* __restrict__ h2) {
    __shared__ float Wls[3][HID][OUTF];
    __shared__ __half cl[8][HID];
    int t = threadIdx.x;
    {
        const float4* w40 = reinterpret_cast<const float4*>(W11);
        const float4* w41 = reinterpret_cast<const float4*>(W22);
        const float4* w42 = reinterpret_cast<const float4*>(W33);
        float4* d0 = reinterpret_cast<float4*>(&Wls[0][0][0]);
        float4* d1 = reinterpret_cast<float4*>(&Wls[1][0][0]);
        float4* d2 = reinterpret_cast<float4*>(&Wls[2][0][0]);
#pragma unroll
        for (int j = 0; j < 2; ++j) {
            d0[t + j * 256] = w40[t + j * 256];
            d1[t + j * 256] = w41[t + j * 256];
            d2[t + j * 256] = w42[t + j * 256];
        }
    }
    int row0 = blockIdx.x * 8;
    ((u32*)cl)[t] = ((const u32*)(comb + (size_t)row0 * HID))[t];
    __syncthreads();

    int col = t & 31;
    int rr  = t >> 5;
    int row = row0 + rr;
    float a0 = 0.f, a1 = 0.f, a2 = 0.f;
    for (int k = 0; k < HID; ++k) {
        float cv = __half2float(cl[rr][k]);
        a0 = fmaf(cv, Wls[0][k][col], a0);
        a1 = fmaf(cv, Wls[1][k][col], a1);
        a2 = fmaf(cv, Wls[2][k][col], a2);
    }
    float d0 = dinv[row], d1 = dinv[NN + row], d2 = dinv[2 * NN + row];
    h2[(size_t)0 * NN * OUTF + (size_t)row * OUTF + col] = __float2half(a0 * d0);
    h2[(size_t)1 * NN * OUTF + (size_t)row * OUTF + col] = __float2half(a1 * d1);
    h2[(size_t)2 * NN * OUTF + (size_t)row * OUTF + col] = __float2half(a2 * d2);
}

// ---------------- layer-2 aggregation, BRANCH-MAJOR: partial sums ----------------
__global__ __launch_bounds__(256) void k_agg2p(
        const u32* __restrict__ csr, const u32* __restrict__ nodeinfo,
        const float* __restrict__ dinv,
        const __half* __restrict__ h2, float* __restrict__ outp) {
    int bid = blockIdx.x;
    int br  = bid / NBLK;
    int nb  = bid - br * NBLK;
    int t   = threadIdx.x;
    int f2  = t & 15;
    int eo  = (t >> 4) & 3;
    int sub = __builtin_amdgcn_readfirstlane(t >> 6);
    int n   = nb * 4 + sub;

    int i   = br * NN + n;
    u32 inf = nodeinfo[i];
    int cc  = (int)(inf & 1023u);
    int st  = (int)(inf >> 10);
    const __half2* h2b = (const __half2*)(h2 + (size_t)br * NN * OUTF);
    float ax = 0.f, ay = 0.f;
    int cm1 = cc - 1;
    for (int j = 0; j < cc; j += 16) {
        u32 ee[4]; __half2 vv[4];
#pragma unroll
        for (int u = 0; u < 4; ++u) {
            int jj = j + 4 * u + eo;
            ee[u] = csr[st + (jj < cm1 ? jj : cm1)];
            if (jj >= cc) ee[u] &= 0xffffu;
        }
#pragma unroll
        for (int u = 0; u < 4; ++u)
            vv[u] = h2b[(size_t)(ee[u] & 0xffff) * 16 + f2];
#pragma unroll
        for (int u = 0; u < 4; ++u) {
            float w = __half2float(__ushort_as_half((u16)(ee[u] >> 16)));
            float2 v = __half22float2(vv[u]);
            ax = fmaf(w, v.x, ax);
            ay = fmaf(w, v.y, ay);
        }
    }
    ax += __shfl_xor(ax, 16); ay += __shfl_xor(ay, 16);
    ax += __shfl_xor(ax, 32); ay += __shfl_xor(ay, 32);
    float d = dinv[i];
    float2 hs = __half22float2(h2b[(size_t)n * 16 + f2]);
    if (eo == 0)
        ((float2*)outp)[((size_t)br * NN + n) * 16 + f2] =
            make_float2(d * (ax + hs.x), d * (ay + hs.y));
}

// ---------------- final sum ----------------
__global__ __launch_bounds__(256) void k_sum(
        const float* __restrict__ outp,
        const float* __restrict__ b11, const float* __restrict__ b22, const float* __restrict__ b33,
        float* __restrict__ out) {
    int i = blockIdx.x * 256 + threadIdx.x;
    int f2 = i & 15;
    const float2* p = (const float2*)outp;
    float2 v0 = p[i];
    float2 v1 = p[(size_t)NN * 16 + i];
    float2 v2 = p[(size_t)2 * NN * 16 + i];
    float2 bA = ((const float2*)b11)[f2];
    float2 bB = ((const float2*)b22)[f2];
    float2 bC = ((const float2*)b33)[f2];
    ((float2*)out)[i] = make_float2(v0.x + v1.x + v2.x + bA.x + bB.x + bC.x,
                                    v0.y + v1.y + v2.y + bA.y + bB.y + bC.y);
}

// ---------------- launch ----------------
extern "C" void kernel_launch(void* const* d_in, const int* in_sizes, int n_in,
                              void* d_out, int out_size, void* d_ws, size_t ws_size,
                              hipStream_t stream) {
    const float* x1  = (const float*)d_in[0];
    const float* x2  = (const float*)d_in[1];
    const float* x3  = (const float*)d_in[2];
    const int*   ei1 = (const int*)d_in[3];
    const int*   ei2 = (const int*)d_in[4];
    const int*   ei3 = (const int*)d_in[5];
    const float* ew1 = (const float*)d_in[6];
    const float* ew2 = (const float*)d_in[7];
    const float* ew3 = (const float*)d_in[8];
    const float* W1  = (const float*)d_in[9];
    const float* W2  = (const float*)d_in[10];
    const float* W3  = (const float*)d_in[11];
    const float* b1  = (const float*)d_in[12];
    const float* b2  = (const float*)d_in[13];
    const float* b3  = (const float*)d_in[14];
    const float* fcw = (const float*)d_in[15];
    const float* fcb = (const float*)d_in[16];
    const float* W11 = (const float*)d_in[17];
    const float* W22 = (const float*)d_in[18];
    const float* W33 = (const float*)d_in[19];
    const float* b11 = (const float*)d_in[20];
    const float* b22 = (const float*)d_in[21];
    const float* b33 = (const float*)d_in[22];

    float* out = (float*)d_out;
    float* coef_out = out + (size_t)NN * OUTF;

    // workspace layout; outp aliases bucketed (dead after k_bucket)
    u64*   bucketed  = (u64*)d_ws;
    float* outp      = (float*)d_ws;
    u32*   csr       = (u32*)(bucketed + 3 * EE);
    u32*   bin_total = csr + 3 * EE;
    u32*   binstart  = bin_total + NBIN;
    u32*   blockbase = binstart + NBIN + 4;
    float* dinv      = (float*)(blockbase + NCNT * NBKT);
    u32*   nodeinfo  = (u32*)(dinv + TOTN);
    f16*   Wt2       = (f16*)(nodeinfo + TOTN);
    __half* h        = (__half*)(Wt2 + 3 * 16384);
    __half* comb     = h + (size_t)TOTN * HID;
    __half* h2       = comb + (size_t)NN * HID;
    __half* e        = h2 + (size_t)TOTN * OUTF;

    k_prep<<<dim3(4), 256, 0, stream>>>(W1, W2, W3, Wt2, bin_total);
    k_count<<<dim3(NCNT), 256, 0, stream>>>(ei1, ei2, ei3, bin_total, blockbase);
    k_scan<<<dim3(1), 256, 0, stream>>>(bin_total, binstart);
    k_scatgemm<<<dim3(NCNT * 5), 256, 0, stream>>>(ei1, ei2, ei3, ew1, ew2, ew3,
                                                   binstart, blockbase, bucketed,
                                                   x1, x2, x3, Wt2, h);
    k_bucket<<<dim3(NBIN), 256, 0, stream>>>(bucketed, bin_total, binstart,
                                             nodeinfo, dinv, csr, h);

    k_agg1<<<dim3(3 * NBLK), 256, 0, stream>>>(csr, nodeinfo, dinv, b1, b2, b3, h, e);
    k_attn<<<dim3(NN / 8), 256, 0, stream>>>(e, fcw, fcb, comb, coef_out);
    k_gemm2<<<dim3(NN / 8), 256, 0, stream>>>(comb, W11, W22, W33, dinv, h2);
    k_agg2p<<<dim3(3 * NBLK), 256, 0, stream>>>(csr, nodeinfo, dinv, h2, outp);
    k_sum<<<dim3(3125), 256, 0, stream>>>(outp, b11, b22, b33, out);
}

// Round 16
// 254.060 us; speedup vs baseline: 1.2584x; 1.0726x over previous
//
#include <hip/hip_runtime.h>
#include <hip/hip_fp16.h>
#include <math.h>

#define NN    50000
#define INF_  256
#define HID   64
#define OUTF  32
#define EE    800000
#define TOTN  (3 * NN)
#define NBKT  196
#define NBIN  (3 * NBKT)     // 588
#define CBLK  196            // scatter chunks per branch (4096 edges each)
#define NCNT  (3 * CBLK)     // 588
#define GB    782
#define NGEMM (3 * GB)       // 2346
#define MAXB  5120           // fixed slots per bin (mean fill 4082, max ~4500)
#define NBLK  12500

typedef unsigned long long u64;
typedef unsigned int       u32;
typedef unsigned short     u16;
typedef _Float16           f16;
typedef f16   f16x8 __attribute__((ext_vector_type(8)));
typedef f16   f16x4 __attribute__((ext_vector_type(4)));
typedef float f32x4 __attribute__((ext_vector_type(4)));

// ---------------- prep: zero bin cursors + swizzle W -> fragment-major Wt2 ----------------
__global__ __launch_bounds__(256) void k_prep(
        const float* __restrict__ W1, const float* __restrict__ W2, const float* __restrict__ W3,
        f16* __restrict__ Wt2, u32* __restrict__ bin_cursor) {
    int blk = blockIdx.x, t = threadIdx.x;
    if (blk == 3) {
        for (int i = t; i < NBIN; i += 256) bin_cursor[i] = 0;
        return;
    }
    const float* W = (blk == 0) ? W1 : (blk == 1) ? W2 : W3;
    f16* wt = Wt2 + blk * 16384;
    for (int idx = t; idx < 16384; idx += 256) {
        int e    = idx & 7;
        int lane = (idx >> 3) & 63;
        int kt   = (idx >> 9) & 7;
        int c    = idx >> 12;
        int col  = c * 16 + (lane & 15);
        int k    = kt * 32 + ((lane >> 4) << 3) + e;
        wt[idx] = (f16)W[k * HID + col];
    }
}

// ---------------- fused: LDS-reordered scatter (fixed-stride bins) + MFMA gemm ----------------
// period 5: r==4 -> scatter chunk q in [0,588); else gemm gid=q*4+r.
// Scatter claims bin space via ONE atomicAdd per (block,bin) on bin_cursor —
// no global count/scan pre-pass needed (k_bucket re-sorts per-node anyway).
__global__ __launch_bounds__(256) void k_scatgemm(
        const int* __restrict__ ei1, const int* __restrict__ ei2, const int* __restrict__ ei3,
        const float* __restrict__ ew1, const float* __restrict__ ew2, const float* __restrict__ ew3,
        u32* __restrict__ bin_cursor, u64* __restrict__ bucketed,
        const float* __restrict__ x1, const float* __restrict__ x2, const float* __restrict__ x3,
        const f16* __restrict__ Wt2, __half* __restrict__ h) {
    __shared__ __align__(16) char smem[36864];   // 36 KB -> 4 blocks/CU
    int bid = blockIdx.x;
    int q = bid / 5, r = bid - q * 5;
    int t = threadIdx.x;

    if (r == 4) {                   // ---- scatter chunk (q in [0,588)) ----
        u64* ent  = (u64*)smem;                    // 4096 x 8B = 32 KB
        u32* acnt = (u32*)(smem + 32768);          // 256
        u32* ascn = acnt + 256;                    // 256
        u32* acur = ascn + 256;                    // 256
        u32* adel = acur + 256;                    // 256
        int cb  = q;
        int br  = cb / CBLK;
        int blk = cb - br * CBLK;
        const int*   ei = (br == 0) ? ei1 : (br == 1) ? ei2 : ei3;
        const float* ew = (br == 0) ? ew1 : (br == 1) ? ew2 : ew3;
        acnt[t] = 0; acur[t] = 0;
        __syncthreads();
        int e0 = blk * 4096;
        int tot = EE - e0; if (tot > 4096) tot = 4096;
        // pass 1: histogram, stash dst in registers
        u32 dstv[16];
#pragma unroll
        for (int k = 0; k < 16; ++k) {
            int e = e0 + k * 256 + t;
            if (e < EE) {
                dstv[k] = (u32)ei[EE + e];
                atomicAdd(&acnt[dstv[k] >> 8], 1u);
            }
        }
        __syncthreads();
        // inclusive scan of acnt -> ascn
        ascn[t] = acnt[t];
        __syncthreads();
        for (int d = 1; d < 256; d <<= 1) {
            u32 v = (t >= d) ? ascn[t - d] : 0;
            __syncthreads();
            ascn[t] += v;
            __syncthreads();
        }
        // claim bin space: one atomic per (block,bin); delta = global_pos - local_pos
        if (t < NBKT) {
            u32 cnt = acnt[t];
            u32 base = cnt ? atomicAdd(&bin_cursor[br * NBKT + t], cnt) : 0;
            adel[t] = (u32)(br * NBKT + t) * MAXB + base - (ascn[t] - acnt[t]);
        }
        __syncthreads();
        // pass 2: reorder into LDS in bucket order (src/ew read; dst from regs)
#pragma unroll
        for (int k = 0; k < 16; ++k) {
            int e = e0 + k * 256 + t;
            if (e < EE) {
                u32 dst = dstv[k];
                u32 src = (u32)ei[e];
                u32 bkt = dst >> 8;
                u16 w16 = __half_as_ushort(__float2half(ew[e]));
                u32 rnk = atomicAdd(&acur[bkt], 1u);
                u32 ls  = ascn[bkt] - acnt[bkt] + rnk;
                ent[ls] = ((u64)bkt << 48) | ((u64)w16 << 32)
                        | ((u64)src << 8) | (u64)(dst & 0xffu);
            }
        }
        __syncthreads();
        // linear write-out: consecutive threads -> consecutive slots within runs
        for (int i = t; i < tot; i += 256) {
            u64 ev = ent[i];
            u32 bkt = (u32)(ev >> 48) & 0xffu;
            bucketed[adel[bkt] + i] = ev;
        }
        return;
    }

    // ---- gemm: gid in [0, NGEMM) ----
    int gid = q * 4 + r;
    if (gid >= NGEMM) return;
    f16 (*xl)[264] = reinterpret_cast<f16(*)[264]>(smem);   // 33792 B
    int b = gid / GB;
    int row_base = (gid - b * GB) * 64;
    const float4* x4 = reinterpret_cast<const float4*>((b == 0) ? x1 : (b == 1) ? x2 : x3);
    const f16* wt2 = Wt2 + b * 16384;
    __half* hb = h + (size_t)b * NN * HID;

    float4 v[16];
#pragma unroll
    for (int j = 0; j < 16; ++j) {
        int flat = j * 256 + t;
        int gr = row_base + (flat >> 6);
        v[j] = (gr < NN) ? x4[(size_t)row_base * 64 + flat]
                         : make_float4(0.f, 0.f, 0.f, 0.f);
    }
#pragma unroll
    for (int j = 0; j < 16; ++j) {
        int flat = j * 256 + t;
        int rr = flat >> 6, c4 = flat & 63;
        f16x4 p = {(f16)v[j].x, (f16)v[j].y, (f16)v[j].z, (f16)v[j].w};
        *(f16x4*)&xl[rr][c4 * 4] = p;
    }
    __syncthreads();                 // only barrier in gemm path

    int w    = t >> 6;
    int lane = t & 63;
    int lrow = lane & 15;
    int lk   = (lane >> 4) * 8;
    int arow = (w << 4) + lrow;

    f32x4 acc[4] = {{0,0,0,0},{0,0,0,0},{0,0,0,0},{0,0,0,0}};
#pragma unroll
    for (int kt = 0; kt < 8; ++kt) {
        f16x8 af = *(const f16x8*)&xl[arow][kt * 32 + lk];
#pragma unroll
        for (int c = 0; c < 4; ++c) {
            f16x8 bf = *(const f16x8*)&wt2[((c * 8 + kt) * 64 + lane) * 8];
            acc[c] = __builtin_amdgcn_mfma_f32_16x16x32_f16(af, bf, acc[c], 0, 0, 0);
        }
    }
    int orow0 = row_base + (w << 4) + ((lane >> 4) << 2);
#pragma unroll
    for (int c = 0; c < 4; ++c) {
#pragma unroll
        for (int i = 0; i < 4; ++i) {
            int row = orow0 + i;
            if (row < NN) hb[(size_t)row * HID + c * 16 + lrow] = __float2half(acc[c][i]);
        }
    }
}

// ---------------- per-bucket: nodeinfo/dinv/CSR in LDS + h-prescale ----------------
__global__ __launch_bounds__(256) void k_bucket(
        const u64* __restrict__ bucketed, const u32* __restrict__ bin_cursor,
        u32* __restrict__ nodeinfo, float* __restrict__ dinv,
        u32* __restrict__ csr, __half* __restrict__ h) {
    __shared__ u32   scnt[256];
    __shared__ float swsum[256];
    __shared__ u32   scur[256];
    __shared__ u32   sscan[256];
    __shared__ float sdiv[256];
    __shared__ u32   lcsr[MAXB];
    int bin = blockIdx.x;
    int br  = bin / NBKT;
    int bkt = bin - br * NBKT;
    int t = threadIdx.x;
    u32 base = (u32)bin * MAXB;          // fixed-stride bin region
    u32 ecnt = bin_cursor[bin];          // final cursor value = bin fill
    scnt[t] = 0; swsum[t] = 0.f; scur[t] = 0;
    __syncthreads();
    for (u32 i = t; i < ecnt; i += 256) {
        u64 e = bucketed[base + i];
        u32 dl = (u32)e & 0xffu;
        atomicAdd(&scnt[dl], 1u);
        atomicAdd(&swsum[dl], __half2float(__ushort_as_half((u16)((e >> 32) & 0xffffu))));
    }
    __syncthreads();
    sscan[t] = scnt[t];
    __syncthreads();
    for (int d = 1; d < 256; d <<= 1) {
        u32 v = (t >= d) ? sscan[t - d] : 0;
        __syncthreads();
        sscan[t] += v;
        __syncthreads();
    }
    u32 lstart = sscan[t] - scnt[t];
    float d = rsqrtf(1.0f + swsum[t]);
    sdiv[t] = d;
    int n = bkt * 256 + t;
    if (n < NN) {
        int gi = br * NN + n;
        nodeinfo[gi] = ((base + lstart) << 10) | scnt[t];
        dinv[gi]     = d;
    }
    __syncthreads();
    for (u32 i = t; i < ecnt; i += 256) {
        u64 e = bucketed[base + i];
        u32 dl  = (u32)e & 0xffu;
        u32 src = (u32)(e >> 8) & 0xffffu;
        u32 w16 = (u32)(e >> 32) & 0xffffu;
        u32 rnk = atomicAdd(&scur[dl], 1u);
        u32 ls  = sscan[dl] - scnt[dl];
        lcsr[ls + rnk] = (w16 << 16) | src;
    }
    __syncthreads();
    for (u32 i = t; i < ecnt; i += 256) csr[base + i] = lcsr[i];

    int nrows = NN - bkt * 256; if (nrows > 256) nrows = 256;
    u32* hrow = (u32*)(h + ((size_t)br * NN + (size_t)bkt * 256) * HID);
    for (int i = t; i < nrows * 32; i += 256) {
        float dd = sdiv[i >> 5];
        __half2 hv = *(__half2*)&hrow[i];
        float2 v = __half22float2(hv);
        __half2 rr = __float22half2_rn(make_float2(v.x * dd, v.y * dd));
        hrow[i] = *(u32*)&rr;
    }
}

// ---------------- layer-1 aggregation, BRANCH-MAJOR: e = ReLU(...) ----------------
__global__ __launch_bounds__(256) void k_agg1(
        const u32* __restrict__ csr, const u32* __restrict__ nodeinfo,
        const float* __restrict__ dinv,
        const float* __restrict__ b1, const float* __restrict__ b2, const float* __restrict__ b3,
        const __half* __restrict__ h, __half* __restrict__ e) {
    int bid = blockIdx.x;
    int br  = bid / NBLK;
    int nb  = bid - br * NBLK;
    int t   = threadIdx.x;
    int f2  = t & 31;
    int eo  = (t >> 5) & 1;
    int sub = __builtin_amdgcn_readfirstlane(t >> 6);
    int n   = nb * 4 + sub;

    const float* bi = (br == 0) ? b1 : (br == 1) ? b2 : b3;
    const __half2* hb2 = (const __half2*)(h + (size_t)br * NN * HID);
    int i   = br * NN + n;
    u32 inf = nodeinfo[i];
    int cc  = (int)(inf & 1023u);
    int st  = (int)(inf >> 10);
    float d = dinv[i];
    float2 hs = __half22float2(hb2[(size_t)n * 32 + f2]);

    float ax = 0.f, ay = 0.f;
    int cm1 = cc - 1;
    for (int j = 0; j < cc; j += 16) {
        u32 ee[8]; __half2 vv[8];
#pragma unroll
        for (int u = 0; u < 8; ++u) {
            int jj = j + 2 * u + eo;
            ee[u] = csr[st + (jj < cm1 ? jj : cm1)];
            if (jj >= cc) ee[u] &= 0xffffu;
        }
#pragma unroll
        for (int u = 0; u < 8; ++u)
            vv[u] = hb2[(size_t)(ee[u] & 0xffff) * 32 + f2];
#pragma unroll
        for (int u = 0; u < 8; ++u) {
            float w = __half2float(__ushort_as_half((u16)(ee[u] >> 16)));
            float2 v = __half22float2(vv[u]);
            ax = fmaf(w, v.x, ax);
            ay = fmaf(w, v.y, ay);
        }
    }
    ax += __shfl_xor(ax, 32);
    ay += __shfl_xor(ay, 32);
    float2 bv = ((const float2*)bi)[f2];
    float ex = fmaxf(bv.x + d * (hs.x + ax), 0.f);
    float ey = fmaxf(bv.y + d * (hs.y + ay), 0.f);
    if (eo == 0)
        ((__half2*)e)[((size_t)br * NN + n) * 32 + f2] = __float22half2_rn(make_float2(ex, ey));
}

// ---------------- attention: coefs + comb from e ----------------
__global__ __launch_bounds__(256) void k_attn(
        const __half* __restrict__ e,
        const float* __restrict__ fc_w, const float* __restrict__ fc_b,
        __half* __restrict__ comb, float* __restrict__ coef_out) {
    int t    = threadIdx.x;
    int lane = t & 63;
    int sub  = __builtin_amdgcn_readfirstlane(t >> 6);
    int half = lane >> 5;
    int f2   = lane & 31;
    int n    = blockIdx.x * 8 + sub * 2 + half;
    float2 wv = ((const float2*)fc_w)[f2];
    float fb = fc_b[0];
    const __half2* e2 = (const __half2*)e;

    float2 ev[3]; float c[3];
#pragma unroll
    for (int b = 0; b < 3; ++b) {
        ev[b] = __half22float2(e2[((size_t)b * NN + n) * 32 + f2]);
        float dd = ev[b].x * wv.x + ev[b].y * wv.y;
#pragma unroll
        for (int off = 16; off > 0; off >>= 1) dd += __shfl_xor(dd, off);
        float z = dd + fb;
        z = (z > 0.f) ? z : 0.01f * z;
        c[b] = expf(z);
    }
    float cd = c[0] + c[1] + c[2];
    float coef0 = c[0] / cd, coef1 = c[1] / cd, coef2 = c[2] / cd;
    float cx = ev[0].x * coef0 + ev[1].x * coef1 + ev[2].x * coef2;
    float cy = ev[0].y * coef0 + ev[1].y * coef1 + ev[2].y * coef2;
    ((__half2*)comb)[(size_t)n * 32 + f2] = __float22half2_rn(make_float2(cx, cy));
    if (f2 == 0) {
        coef_out[n]          = coef0;
        coef_out[NN + n]     = coef1;
        coef_out[2 * NN + n] = coef2;
    }
}

// ---------------- layer-2 GEMM: h2'[b] = dinv * (comb @ W_b) ----------------
__global__ __launch_bounds__(256) void k_gemm2(
        const __half* __restrict__ comb,
        const float* __restrict__ W11, const float* __restrict__ W22, const float* __restrict__ W33,
        const float* __restrict__ dinv, __half* __restrict__ h2) {
    __shared__ float Wls[3][HID][OUTF];
    __shared__ __half cl[8][HID];
    int t = threadIdx.x;
    {
        const float4* w40 = reinterpret_cast<const float4*>(W11);
        const float4* w41 = reinterpret_cast<const float4*>(W22);
        const float4* w42 = reinterpret_cast<const float4*>(W33);
        float4* d0 = reinterpret_cast<float4*>(&Wls[0][0][0]);
        float4* d1 = reinterpret_cast<float4*>(&Wls[1][0][0]);
        float4* d2 = reinterpret_cast<float4*>(&Wls[2][0][0]);
#pragma unroll
        for (int j = 0; j < 2; ++j) {
            d0[t + j * 256] = w40[t + j * 256];
            d1[t + j * 256] = w41[t + j * 256];
            d2[t + j * 256] = w42[t + j * 256];
        }
    }
    int row0 = blockIdx.x * 8;
    ((u32*)cl)[t] = ((const u32*)(comb + (size_t)row0 * HID))[t];
    __syncthreads();

    int col = t & 31;
    int rr  = t >> 5;
    int row = row0 + rr;
    float a0 = 0.f, a1 = 0.f, a2 = 0.f;
    for (int k = 0; k < HID; ++k) {
        float cv = __half2float(cl[rr][k]);
        a0 = fmaf(cv, Wls[0][k][col], a0);
        a1 = fmaf(cv, Wls[1][k][col], a1);
        a2 = fmaf(cv, Wls[2][k][col], a2);
    }
    float d0 = dinv[row], d1 = dinv[NN + row], d2 = dinv[2 * NN + row];
    h2[(size_t)0 * NN * OUTF + (size_t)row * OUTF + col] = __float2half(a0 * d0);
    h2[(size_t)1 * NN * OUTF + (size_t)row * OUTF + col] = __float2half(a1 * d1);
    h2[(size_t)2 * NN * OUTF + (size_t)row * OUTF + col] = __float2half(a2 * d2);
}

// ---------------- layer-2 aggregation, BRANCH-MAJOR: partial sums ----------------
__global__ __launch_bounds__(256) void k_agg2p(
        const u32* __restrict__ csr, const u32* __restrict__ nodeinfo,
        const float* __restrict__ dinv,
        const __half* __restrict__ h2, float* __restrict__ outp) {
    int bid = blockIdx.x;
    int br  = bid / NBLK;
    int nb  = bid - br * NBLK;
    int t   = threadIdx.x;
    int f2  = t & 15;
    int eo  = (t >> 4) & 3;
    int sub = __builtin_amdgcn_readfirstlane(t >> 6);
    int n   = nb * 4 + sub;

    int i   = br * NN + n;
    u32 inf = nodeinfo[i];
    int cc  = (int)(inf & 1023u);
    int st  = (int)(inf >> 10);
    const __half2* h2b = (const __half2*)(h2 + (size_t)br * NN * OUTF);
    float ax = 0.f, ay = 0.f;
    int cm1 = cc - 1;
    for (int j = 0; j < cc; j += 16) {
        u32 ee[4]; __half2 vv[4];
#pragma unroll
        for (int u = 0; u < 4; ++u) {
            int jj = j + 4 * u + eo;
            ee[u] = csr[st + (jj < cm1 ? jj : cm1)];
            if (jj >= cc) ee[u] &= 0xffffu;
        }
#pragma unroll
        for (int u = 0; u < 4; ++u)
            vv[u] = h2b[(size_t)(ee[u] & 0xffff) * 16 + f2];
#pragma unroll
        for (int u = 0; u < 4; ++u) {
            float w = __half2float(__ushort_as_half((u16)(ee[u] >> 16)));
            float2 v = __half22float2(vv[u]);
            ax = fmaf(w, v.x, ax);
            ay = fmaf(w, v.y, ay);
        }
    }
    ax += __shfl_xor(ax, 16); ay += __shfl_xor(ay, 16);
    ax += __shfl_xor(ax, 32); ay += __shfl_xor(ay, 32);
    float d = dinv[i];
    float2 hs = __half22float2(h2b[(size_t)n * 16 + f2]);
    if (eo == 0)
        ((float2*)outp)[((size_t)br * NN + n) * 16 + f2] =
            make_float2(d * (ax + hs.x), d * (ay + hs.y));
}

// ---------------- final sum ----------------
__global__ __launch_bounds__(256) void k_sum(
        const float* __restrict__ outp,
        const float* __restrict__ b11, const float* __restrict__ b22, const float* __restrict__ b33,
        float* __restrict__ out) {
    int i = blockIdx.x * 256 + threadIdx.x;
    int f2 = i & 15;
    const float2* p = (const float2*)outp;
    float2 v0 = p[i];
    float2 v1 = p[(size_t)NN * 16 + i];
    float2 v2 = p[(size_t)2 * NN * 16 + i];
    float2 bA = ((const float2*)b11)[f2];
    float2 bB = ((const float2*)b22)[f2];
    float2 bC = ((const float2*)b33)[f2];
    ((float2*)out)[i] = make_float2(v0.x + v1.x + v2.x + bA.x + bB.x + bC.x,
                                    v0.y + v1.y + v2.y + bA.y + bB.y + bC.y);
}

// ---------------- launch ----------------
extern "C" void kernel_launch(void* const* d_in, const int* in_sizes, int n_in,
                              void* d_out, int out_size, void* d_ws, size_t ws_size,
                              hipStream_t stream) {
    const float* x1  = (const float*)d_in[0];
    const float* x2  = (const float*)d_in[1];
    const float* x3  = (const float*)d_in[2];
    const int*   ei1 = (const int*)d_in[3];
    const int*   ei2 = (const int*)d_in[4];
    const int*   ei3 = (const int*)d_in[5];
    const float* ew1 = (const float*)d_in[6];
    const float* ew2 = (const float*)d_in[7];
    const float* ew3 = (const float*)d_in[8];
    const float* W1  = (const float*)d_in[9];
    const float* W2  = (const float*)d_in[10];
    const float* W3  = (const float*)d_in[11];
    const float* b1  = (const float*)d_in[12];
    const float* b2  = (const float*)d_in[13];
    const float* b3  = (const float*)d_in[14];
    const float* fcw = (const float*)d_in[15];
    const float* fcb = (const float*)d_in[16];
    const float* W11 = (const float*)d_in[17];
    const float* W22 = (const float*)d_in[18];
    const float* W33 = (const float*)d_in[19];
    const float* b11 = (const float*)d_in[20];
    const float* b22 = (const float*)d_in[21];
    const float* b33 = (const float*)d_in[22];

    float* out = (float*)d_out;
    float* coef_out = out + (size_t)NN * OUTF;

    // workspace layout; outp aliases bucketed (dead after k_bucket)
    u64*   bucketed  = (u64*)d_ws;                           // 588*5120 u64 = 24.1 MB
    float* outp      = (float*)d_ws;                         // 3N*32 f32 = 19.2 MB (alias)
    u32*   csr       = (u32*)(bucketed + (size_t)NBIN * MAXB);  // 588*5120 u32 = 12 MB
    u32*   bin_cursor= csr + (size_t)NBIN * MAXB;            // 588
    float* dinv      = (float*)(bin_cursor + NBIN + 4);      // 3N
    u32*   nodeinfo  = (u32*)(dinv + TOTN);                  // 3N
    f16*   Wt2       = (f16*)(nodeinfo + TOTN);              // 3*16384
    __half* h        = (__half*)(Wt2 + 3 * 16384);           // 3N*64    19.2 MB
    __half* comb     = h + (size_t)TOTN * HID;               // N*64      6.4 MB
    __half* h2       = comb + (size_t)NN * HID;              // 3N*32     9.6 MB
    __half* e        = h2 + (size_t)TOTN * OUTF;             // 3N*64    19.2 MB

    k_prep<<<dim3(4), 256, 0, stream>>>(W1, W2, W3, Wt2, bin_cursor);
    k_scatgemm<<<dim3(NCNT * 5), 256, 0, stream>>>(ei1, ei2, ei3, ew1, ew2, ew3,
                                                   bin_cursor, bucketed,
                                                   x1, x2, x3, Wt2, h);
    k_bucket<<<dim3(NBIN), 256, 0, stream>>>(bucketed, bin_cursor,
                                             nodeinfo, dinv, csr, h);

    k_agg1<<<dim3(3 * NBLK), 256, 0, stream>>>(csr, nodeinfo, dinv, b1, b2, b3, h, e);
    k_attn<<<dim3(NN / 8), 256, 0, stream>>>(e, fcw, fcb, comb, coef_out);
    k_gemm2<<<dim3(NN / 8), 256, 0, stream>>>(comb, W11, W22, W33, dinv, h2);
    k_agg2p<<<dim3(3 * NBLK), 256, 0, stream>>>(csr, nodeinfo, dinv, h2, outp);
    k_sum<<<dim3(3125), 256, 0, stream>>>(outp, b11, b22, b33, out);
}

// Round 17
// 246.894 us; speedup vs baseline: 1.2950x; 1.0290x over previous
//
#include <hip/hip_runtime.h>
#include <hip/hip_fp16.h>
#include <math.h>

#define NN    50000
#define INF_  256
#define HID   64
#define OUTF  32
#define EE    800000
#define TOTN  (3 * NN)
#define NBKT  196
#define NBIN  (3 * NBKT)     // 588
#define CBLK  391            // scatter chunks per branch (2048 edges each; 391*2048 >= EE)
#define NCNT  (3 * CBLK)     // 1173
#define GB    1563           // gemm tiles per branch (32 rows each)
#define NGEMM (3 * GB)       // 4689
#define MAXB  5120           // fixed slots per bin
#define NBLK  12500

typedef unsigned long long u64;
typedef unsigned int       u32;
typedef unsigned short     u16;
typedef _Float16           f16;
typedef f16   f16x8 __attribute__((ext_vector_type(8)));
typedef f16   f16x4 __attribute__((ext_vector_type(4)));
typedef float f32x4 __attribute__((ext_vector_type(4)));

// ---------------- prep: zero bin cursors + swizzle W -> fragment-major Wt2 ----------------
__global__ __launch_bounds__(256) void k_prep(
        const float* __restrict__ W1, const float* __restrict__ W2, const float* __restrict__ W3,
        f16* __restrict__ Wt2, u32* __restrict__ bin_cursor) {
    int blk = blockIdx.x, t = threadIdx.x;
    if (blk == 3) {
        for (int i = t; i < NBIN; i += 256) bin_cursor[i] = 0;
        return;
    }
    const float* W = (blk == 0) ? W1 : (blk == 1) ? W2 : W3;
    f16* wt = Wt2 + blk * 16384;
    for (int idx = t; idx < 16384; idx += 256) {
        int e    = idx & 7;
        int lane = (idx >> 3) & 63;
        int kt   = (idx >> 9) & 7;
        int c    = idx >> 12;
        int col  = c * 16 + (lane & 15);
        int k    = kt * 32 + ((lane >> 4) << 3) + e;
        wt[idx] = (f16)W[k * HID + col];
    }
}

// ---------------- fused: LDS-reordered scatter + MFMA gemm, 20KB LDS -> 8 blocks/CU ----------------
// period 5: r==4 -> scatter chunk q in [0,1173); else gemm gid=q*4+r (32-row tiles).
__global__ __launch_bounds__(256) void k_scatgemm(
        const int* __restrict__ ei1, const int* __restrict__ ei2, const int* __restrict__ ei3,
        const float* __restrict__ ew1, const float* __restrict__ ew2, const float* __restrict__ ew3,
        u32* __restrict__ bin_cursor, u64* __restrict__ bucketed,
        const float* __restrict__ x1, const float* __restrict__ x2, const float* __restrict__ x3,
        const f16* __restrict__ Wt2, __half* __restrict__ h) {
    __shared__ __align__(16) char smem[20480];   // 20 KB -> 8 blocks/CU
    int bid = blockIdx.x;
    int q = bid / 5, r = bid - q * 5;
    int t = threadIdx.x;

    if (r == 4) {                   // ---- scatter chunk (q in [0,1173)) ----
        u64* ent  = (u64*)smem;                    // 2048 x 8B = 16 KB
        u32* acnt = (u32*)(smem + 16384);          // 256
        u32* ascn = acnt + 256;                    // 256
        u32* acur = ascn + 256;                    // 256
        u32* adel = acur + 256;                    // 256
        int cb  = q;
        int br  = cb / CBLK;
        int blk = cb - br * CBLK;
        const int*   ei = (br == 0) ? ei1 : (br == 1) ? ei2 : ei3;
        const float* ew = (br == 0) ? ew1 : (br == 1) ? ew2 : ew3;
        acnt[t] = 0; acur[t] = 0;
        __syncthreads();
        int e0 = blk * 2048;
        int tot = EE - e0; if (tot > 2048) tot = 2048; if (tot < 0) tot = 0;
        // pass 1: histogram, stash dst in registers
        u32 dstv[8];
#pragma unroll
        for (int k = 0; k < 8; ++k) {
            int e = e0 + k * 256 + t;
            if (e < EE) {
                dstv[k] = (u32)ei[EE + e];
                atomicAdd(&acnt[dstv[k] >> 8], 1u);
            }
        }
        __syncthreads();
        // inclusive scan of acnt -> ascn
        ascn[t] = acnt[t];
        __syncthreads();
        for (int d = 1; d < 256; d <<= 1) {
            u32 v = (t >= d) ? ascn[t - d] : 0;
            __syncthreads();
            ascn[t] += v;
            __syncthreads();
        }
        // claim bin space: one atomic per (block,bin)
        if (t < NBKT) {
            u32 cnt = acnt[t];
            u32 base = cnt ? atomicAdd(&bin_cursor[br * NBKT + t], cnt) : 0;
            adel[t] = (u32)(br * NBKT + t) * MAXB + base - (ascn[t] - acnt[t]);
        }
        __syncthreads();
        // pass 2: reorder into LDS in bucket order
#pragma unroll
        for (int k = 0; k < 8; ++k) {
            int e = e0 + k * 256 + t;
            if (e < EE) {
                u32 dst = dstv[k];
                u32 src = (u32)ei[e];
                u32 bkt = dst >> 8;
                u16 w16 = __half_as_ushort(__float2half(ew[e]));
                u32 rnk = atomicAdd(&acur[bkt], 1u);
                u32 ls  = ascn[bkt] - acnt[bkt] + rnk;
                ent[ls] = ((u64)bkt << 48) | ((u64)w16 << 32)
                        | ((u64)src << 8) | (u64)(dst & 0xffu);
            }
        }
        __syncthreads();
        // linear write-out
        for (int i = t; i < tot; i += 256) {
            u64 ev = ent[i];
            u32 bkt = (u32)(ev >> 48) & 0xffu;
            bucketed[adel[bkt] + i] = ev;
        }
        return;
    }

    // ---- gemm: gid in [0, NGEMM), 32-row x 64-col tile ----
    int gid = q * 4 + r;
    if (gid >= NGEMM) return;
    f16 (*xl)[264] = reinterpret_cast<f16(*)[264]>(smem);   // 32 x 264 f16 = 16.9 KB
    int b = gid / GB;
    int row_base = (gid - b * GB) * 32;
    const float4* x4 = reinterpret_cast<const float4*>((b == 0) ? x1 : (b == 1) ? x2 : x3);
    const f16* wt2 = Wt2 + b * 16384;
    __half* hb = h + (size_t)b * NN * HID;

    // stage 32x256 x-tile: 2048 float4 = 8 thread-contiguous loads
    float4 v[8];
#pragma unroll
    for (int j = 0; j < 8; ++j) {
        int flat = j * 256 + t;
        int gr = row_base + (flat >> 6);
        v[j] = (gr < NN) ? x4[(size_t)row_base * 64 + flat]
                         : make_float4(0.f, 0.f, 0.f, 0.f);
    }
#pragma unroll
    for (int j = 0; j < 8; ++j) {
        int flat = j * 256 + t;
        int rr = flat >> 6, c4 = flat & 63;
        f16x4 p = {(f16)v[j].x, (f16)v[j].y, (f16)v[j].z, (f16)v[j].w};
        *(f16x4*)&xl[rr][c4 * 4] = p;
    }
    __syncthreads();                 // only barrier in gemm path

    int w      = t >> 6;             // wave 0..3
    int lane   = t & 63;
    int lrow   = lane & 15;
    int lk     = (lane >> 4) * 8;
    int rloc   = (w & 1) * 16;       // row half
    int ctile0 = (w >> 1) * 2;       // col-tile pair
    int arow   = rloc + lrow;

    f32x4 acc[2] = {{0,0,0,0},{0,0,0,0}};
#pragma unroll
    for (int kt = 0; kt < 8; ++kt) {
        f16x8 af = *(const f16x8*)&xl[arow][kt * 32 + lk];
#pragma unroll
        for (int ci = 0; ci < 2; ++ci) {
            int c = ctile0 + ci;
            f16x8 bf = *(const f16x8*)&wt2[((c * 8 + kt) * 64 + lane) * 8];
            acc[ci] = __builtin_amdgcn_mfma_f32_16x16x32_f16(af, bf, acc[ci], 0, 0, 0);
        }
    }
    int orow0 = row_base + rloc + ((lane >> 4) << 2);
#pragma unroll
    for (int ci = 0; ci < 2; ++ci) {
#pragma unroll
        for (int i = 0; i < 4; ++i) {
            int row = orow0 + i;
            if (row < NN)
                hb[(size_t)row * HID + (ctile0 + ci) * 16 + lrow] = __float2half(acc[ci][i]);
        }
    }
}

// ---------------- per-bucket: nodeinfo/dinv/CSR in LDS + h-prescale ----------------
__global__ __launch_bounds__(256) void k_bucket(
        const u64* __restrict__ bucketed, const u32* __restrict__ bin_cursor,
        u32* __restrict__ nodeinfo, float* __restrict__ dinv,
        u32* __restrict__ csr, __half* __restrict__ h) {
    __shared__ u32   scnt[256];
    __shared__ float swsum[256];
    __shared__ u32   scur[256];
    __shared__ u32   sscan[256];
    __shared__ float sdiv[256];
    __shared__ u32   lcsr[MAXB];
    int bin = blockIdx.x;
    int br  = bin / NBKT;
    int bkt = bin - br * NBKT;
    int t = threadIdx.x;
    u32 base = (u32)bin * MAXB;
    u32 ecnt = bin_cursor[bin];
    scnt[t] = 0; swsum[t] = 0.f; scur[t] = 0;
    __syncthreads();
    for (u32 i = t; i < ecnt; i += 256) {
        u64 e = bucketed[base + i];
        u32 dl = (u32)e & 0xffu;
        atomicAdd(&scnt[dl], 1u);
        atomicAdd(&swsum[dl], __half2float(__ushort_as_half((u16)((e >> 32) & 0xffffu))));
    }
    __syncthreads();
    sscan[t] = scnt[t];
    __syncthreads();
    for (int d = 1; d < 256; d <<= 1) {
        u32 v = (t >= d) ? sscan[t - d] : 0;
        __syncthreads();
        sscan[t] += v;
        __syncthreads();
    }
    u32 lstart = sscan[t] - scnt[t];
    float d = rsqrtf(1.0f + swsum[t]);
    sdiv[t] = d;
    int n = bkt * 256 + t;
    if (n < NN) {
        int gi = br * NN + n;
        nodeinfo[gi] = ((base + lstart) << 10) | scnt[t];
        dinv[gi]     = d;
    }
    __syncthreads();
    for (u32 i = t; i < ecnt; i += 256) {
        u64 e = bucketed[base + i];
        u32 dl  = (u32)e & 0xffu;
        u32 src = (u32)(e >> 8) & 0xffffu;
        u32 w16 = (u32)(e >> 32) & 0xffffu;
        u32 rnk = atomicAdd(&scur[dl], 1u);
        u32 ls  = sscan[dl] - scnt[dl];
        lcsr[ls + rnk] = (w16 << 16) | src;
    }
    __syncthreads();
    for (u32 i = t; i < ecnt; i += 256) csr[base + i] = lcsr[i];

    int nrows = NN - bkt * 256; if (nrows > 256) nrows = 256;
    u32* hrow = (u32*)(h + ((size_t)br * NN + (size_t)bkt * 256) * HID);
    for (int i = t; i < nrows * 32; i += 256) {
        float dd = sdiv[i >> 5];
        __half2 hv = *(__half2*)&hrow[i];
        float2 v = __half22float2(hv);
        __half2 rr = __float22half2_rn(make_float2(v.x * dd, v.y * dd));
        hrow[i] = *(u32*)&rr;
    }
}

// ---------------- layer-1 aggregation, BRANCH-MAJOR: e = ReLU(...) ----------------
__global__ __launch_bounds__(256) void k_agg1(
        const u32* __restrict__ csr, const u32* __restrict__ nodeinfo,
        const float* __restrict__ dinv,
        const float* __restrict__ b1, const float* __restrict__ b2, const float* __restrict__ b3,
        const __half* __restrict__ h, __half* __restrict__ e) {
    int bid = blockIdx.x;
    int br  = bid / NBLK;
    int nb  = bid - br * NBLK;
    int t   = threadIdx.x;
    int f2  = t & 31;
    int eo  = (t >> 5) & 1;
    int sub = __builtin_amdgcn_readfirstlane(t >> 6);
    int n   = nb * 4 + sub;

    const float* bi = (br == 0) ? b1 : (br == 1) ? b2 : b3;
    const __half2* hb2 = (const __half2*)(h + (size_t)br * NN * HID);
    int i   = br * NN + n;
    u32 inf = nodeinfo[i];
    int cc  = (int)(inf & 1023u);
    int st  = (int)(inf >> 10);
    float d = dinv[i];
    float2 hs = __half22float2(hb2[(size_t)n * 32 + f2]);

    float ax = 0.f, ay = 0.f;
    int cm1 = cc - 1;
    for (int j = 0; j < cc; j += 16) {
        u32 ee[8]; __half2 vv[8];
#pragma unroll
        for (int u = 0; u < 8; ++u) {
            int jj = j + 2 * u + eo;
            ee[u] = csr[st + (jj < cm1 ? jj : cm1)];
            if (jj >= cc) ee[u] &= 0xffffu;
        }
#pragma unroll
        for (int u = 0; u < 8; ++u)
            vv[u] = hb2[(size_t)(ee[u] & 0xffff) * 32 + f2];
#pragma unroll
        for (int u = 0; u < 8; ++u) {
            float w = __half2float(__ushort_as_half((u16)(ee[u] >> 16)));
            float2 v = __half22float2(vv[u]);
            ax = fmaf(w, v.x, ax);
            ay = fmaf(w, v.y, ay);
        }
    }
    ax += __shfl_xor(ax, 32);
    ay += __shfl_xor(ay, 32);
    float2 bv = ((const float2*)bi)[f2];
    float ex = fmaxf(bv.x + d * (hs.x + ax), 0.f);
    float ey = fmaxf(bv.y + d * (hs.y + ay), 0.f);
    if (eo == 0)
        ((__half2*)e)[((size_t)br * NN + n) * 32 + f2] = __float22half2_rn(make_float2(ex, ey));
}

// ---------------- attention: coefs + comb from e ----------------
__global__ __launch_bounds__(256) void k_attn(
        const __half* __restrict__ e,
        const float* __restrict__ fc_w, const float* __restrict__ fc_b,
        __half* __restrict__ comb, float* __restrict__ coef_out) {
    int t    = threadIdx.x;
    int lane = t & 63;
    int sub  = __builtin_amdgcn_readfirstlane(t >> 6);
    int half = lane >> 5;
    int f2   = lane & 31;
    int n    = blockIdx.x * 8 + sub * 2 + half;
    float2 wv = ((const float2*)fc_w)[f2];
    float fb = fc_b[0];
    const __half2* e2 = (const __half2*)e;

    float2 ev[3]; float c[3];
#pragma unroll
    for (int b = 0; b < 3; ++b) {
        ev[b] = __half22float2(e2[((size_t)b * NN + n) * 32 + f2]);
        float dd = ev[b].x * wv.x + ev[b].y * wv.y;
#pragma unroll
        for (int off = 16; off > 0; off >>= 1) dd += __shfl_xor(dd, off);
        float z = dd + fb;
        z = (z > 0.f) ? z : 0.01f * z;
        c[b] = expf(z);
    }
    float cd = c[0] + c[1] + c[2];
    float coef0 = c[0] / cd, coef1 = c[1] / cd, coef2 = c[2] / cd;
    float cx = ev[0].x * coef0 + ev[1].x * coef1 + ev[2].x * coef2;
    float cy = ev[0].y * coef0 + ev[1].y * coef1 + ev[2].y * coef2;
    ((__half2*)comb)[(size_t)n * 32 + f2] = __float22half2_rn(make_float2(cx, cy));
    if (f2 == 0) {
        coef_out[n]          = coef0;
        coef_out[NN + n]     = coef1;
        coef_out[2 * NN + n] = coef2;
    }
}

// ---------------- layer-2 GEMM: h2'[b] = dinv * (comb @ W_b) ----------------
__global__ __launch_bounds__(256) void k_gemm2(
        const __half* __restrict__ comb,
        const float* __restrict__ W11, const float* __restrict__ W22, const float* __restrict__ W33,
        const float* __restrict__ dinv, __half* __restrict__ h2) {
    __shared__ float Wls[3][HID][OUTF];
    __shared__ __half cl[8][HID];
    int t = threadIdx.x;
    {
        const float4* w40 = reinterpret_cast<const float4*>(W11);
        const float4* w41 = reinterpret_cast<const float4*>(W22);
        const float4* w42 = reinterpret_cast<const float4*>(W33);
        float4* d0 = reinterpret_cast<float4*>(&Wls[0][0][0]);
        float4* d1 = reinterpret_cast<float4*>(&Wls[1][0][0]);
        float4* d2 = reinterpret_cast<float4*>(&Wls[2][0][0]);
#pragma unroll
        for (int j = 0; j < 2; ++j) {
            d0[t + j * 256] = w40[t + j * 256];
            d1[t + j * 256] = w41[t + j * 256];
            d2[t + j * 256] = w42[t + j * 256];
        }
    }
    int row0 = blockIdx.x * 8;
    ((u32*)cl)[t] = ((const u32*)(comb + (size_t)row0 * HID))[t];
    __syncthreads();

    int col = t & 31;
    int rr  = t >> 5;
    int row = row0 + rr;
    float a0 = 0.f, a1 = 0.f, a2 = 0.f;
    for (int k = 0; k < HID; ++k) {
        float cv = __half2float(cl[rr][k]);
        a0 = fmaf(cv, Wls[0][k][col], a0);
        a1 = fmaf(cv, Wls[1][k][col], a1);
        a2 = fmaf(cv, Wls[2][k][col], a2);
    }
    float d0 = dinv[row], d1 = dinv[NN + row], d2 = dinv[2 * NN + row];
    h2[(size_t)0 * NN * OUTF + (size_t)row * OUTF + col] = __float2half(a0 * d0);
    h2[(size_t)1 * NN * OUTF + (size_t)row * OUTF + col] = __float2half(a1 * d1);
    h2[(size_t)2 * NN * OUTF + (size_t)row * OUTF + col] = __float2half(a2 * d2);
}

// ---------------- layer-2 aggregation, BRANCH-MAJOR: partial sums ----------------
__global__ __launch_bounds__(256) void k_agg2p(
        const u32* __restrict__ csr, const u32* __restrict__ nodeinfo,
        const float* __restrict__ dinv,
        const __half* __restrict__ h2, float* __restrict__ outp) {
    int bid = blockIdx.x;
    int br  = bid / NBLK;
    int nb  = bid - br * NBLK;
    int t   = threadIdx.x;
    int f2  = t & 15;
    int eo  = (t >> 4) & 3;
    int sub = __builtin_amdgcn_readfirstlane(t >> 6);
    int n   = nb * 4 + sub;

    int i   = br * NN + n;
    u32 inf = nodeinfo[i];
    int cc  = (int)(inf & 1023u);
    int st  = (int)(inf >> 10);
    const __half2* h2b = (const __half2*)(h2 + (size_t)br * NN * OUTF);
    float ax = 0.f, ay = 0.f;
    int cm1 = cc - 1;
    for (int j = 0; j < cc; j += 16) {
        u32 ee[4]; __half2 vv[4];
#pragma unroll
        for (int u = 0; u < 4; ++u) {
            int jj = j + 4 * u + eo;
            ee[u] = csr[st + (jj < cm1 ? jj : cm1)];
            if (jj >= cc) ee[u] &= 0xffffu;
        }
#pragma unroll
        for (int u = 0; u < 4; ++u)
            vv[u] = h2b[(size_t)(ee[u] & 0xffff) * 16 + f2];
#pragma unroll
        for (int u = 0; u < 4; ++u) {
            float w = __half2float(__ushort_as_half((u16)(ee[u] >> 16)));
            float2 v = __half22float2(vv[u]);
            ax = fmaf(w, v.x, ax);
            ay = fmaf(w, v.y, ay);
        }
    }
    ax += __shfl_xor(ax, 16); ay += __shfl_xor(ay, 16);
    ax += __shfl_xor(ax, 32); ay += __shfl_xor(ay, 32);
    float d = dinv[i];
    float2 hs = __half22float2(h2b[(size_t)n * 16 + f2]);
    if (eo == 0)
        ((float2*)outp)[((size_t)br * NN + n) * 16 + f2] =
            make_float2(d * (ax + hs.x), d * (ay + hs.y));
}

// ---------------- final sum ----------------
__global__ __launch_bounds__(256) void k_sum(
        const float* __restrict__ outp,
        const float* __restrict__ b11, const float* __restrict__ b22, const float* __restrict__ b33,
        float* __restrict__ out) {
    int i = blockIdx.x * 256 + threadIdx.x;
    int f2 = i & 15;
    const float2* p = (const float2*)outp;
    float2 v0 = p[i];
    float2 v1 = p[(size_t)NN * 16 + i];
    float2 v2 = p[(size_t)2 * NN * 16 + i];
    float2 bA = ((const float2*)b11)[f2];
    float2 bB = ((const float2*)b22)[f2];
    float2 bC = ((const float2*)b33)[f2];
    ((float2*)out)[i] = make_float2(v0.x + v1.x + v2.x + bA.x + bB.x + bC.x,
                                    v0.y + v1.y + v2.y + bA.y + bB.y + bC.y);
}

// ---------------- launch ----------------
extern "C" void kernel_launch(void* const* d_in, const int* in_sizes, int n_in,
                              void* d_out, int out_size, void* d_ws, size_t ws_size,
                              hipStream_t stream) {
    const float* x1  = (const float*)d_in[0];
    const float* x2  = (const float*)d_in[1];
    const float* x3  = (const float*)d_in[2];
    const int*   ei1 = (const int*)d_in[3];
    const int*   ei2 = (const int*)d_in[4];
    const int*   ei3 = (const int*)d_in[5];
    const float* ew1 = (const float*)d_in[6];
    const float* ew2 = (const float*)d_in[7];
    const float* ew3 = (const float*)d_in[8];
    const float* W1  = (const float*)d_in[9];
    const float* W2  = (const float*)d_in[10];
    const float* W3  = (const float*)d_in[11];
    const float* b1  = (const float*)d_in[12];
    const float* b2  = (const float*)d_in[13];
    const float* b3  = (const float*)d_in[14];
    const float* fcw = (const float*)d_in[15];
    const float* fcb = (const float*)d_in[16];
    const float* W11 = (const float*)d_in[17];
    const float* W22 = (const float*)d_in[18];
    const float* W33 = (const float*)d_in[19];
    const float* b11 = (const float*)d_in[20];
    const float* b22 = (const float*)d_in[21];
    const float* b33 = (const float*)d_in[22];

    float* out = (float*)d_out;
    float* coef_out = out + (size_t)NN * OUTF;

    // workspace layout; outp aliases bucketed (dead after k_bucket)
    u64*   bucketed  = (u64*)d_ws;                              // 588*5120 u64 = 24.1 MB
    float* outp      = (float*)d_ws;                            // 3N*32 f32 (alias)
    u32*   csr       = (u32*)(bucketed + (size_t)NBIN * MAXB);  // 588*5120 u32 = 12 MB
    u32*   bin_cursor= csr + (size_t)NBIN * MAXB;               // 588
    float* dinv      = (float*)(bin_cursor + NBIN + 4);         // 3N
    u32*   nodeinfo  = (u32*)(dinv + TOTN);                     // 3N
    f16*   Wt2       = (f16*)(nodeinfo + TOTN);                 // 3*16384
    __half* h        = (__half*)(Wt2 + 3 * 16384);              // 3N*64
    __half* comb     = h + (size_t)TOTN * HID;                  // N*64
    __half* h2       = comb + (size_t)NN * HID;                 // 3N*32
    __half* e        = h2 + (size_t)TOTN * OUTF;                // 3N*64

    k_prep<<<dim3(4), 256, 0, stream>>>(W1, W2, W3, Wt2, bin_cursor);
    k_scatgemm<<<dim3(NCNT * 5), 256, 0, stream>>>(ei1, ei2, ei3, ew1, ew2, ew3,
                                                   bin_cursor, bucketed,
                                                   x1, x2, x3, Wt2, h);
    k_bucket<<<dim3(NBIN), 256, 0, stream>>>(bucketed, bin_cursor,
                                             nodeinfo, dinv, csr, h);

    k_agg1<<<dim3(3 * NBLK), 256, 0, stream>>>(csr, nodeinfo, dinv, b1, b2, b3, h, e);
    k_attn<<<dim3(NN / 8), 256, 0, stream>>>(e, fcw, fcb, comb, coef_out);
    k_gemm2<<<dim3(NN / 8), 256, 0, stream>>>(comb, W11, W22, W33, dinv, h2);
    k_agg2p<<<dim3(3 * NBLK), 256, 0, stream>>>(csr, nodeinfo, dinv, h2, outp);
    k_sum<<<dim3(3125), 256, 0, stream>>>(outp, b11, b22, b33, out);
}

// Round 18
// 240.459 us; speedup vs baseline: 1.3296x; 1.0268x over previous
//
#include <hip/hip_runtime.h>
#include <hip/hip_fp16.h>
#include <math.h>

#define NN    50000
#define INF_  256
#define HID   64
#define OUTF  32
#define EE    800000
#define TOTN  (3 * NN)
#define NBKT  196
#define NBIN  (3 * NBKT)     // 588
#define CBLK  391            // scatter chunks per branch (2048 edges)
#define NCNT  (3 * CBLK)     // 1173
#define GB    1563           // gemm tiles per branch (32 rows)
#define NGEMM (3 * GB)       // 4689
#define MAXB  5120
#define NBLK  12500

typedef unsigned long long u64;
typedef unsigned int       u32;
typedef unsigned short     u16;
typedef unsigned char      u8;
typedef _Float16           f16;
typedef f16   f16x8 __attribute__((ext_vector_type(8)));
typedef f16   f16x4 __attribute__((ext_vector_type(4)));
typedef float f32x4 __attribute__((ext_vector_type(4)));

// ---------------- prep: zero bin cursors + swizzle W -> fragment-major Wt2 ----------------
__global__ __launch_bounds__(256) void k_prep(
        const float* __restrict__ W1, const float* __restrict__ W2, const float* __restrict__ W3,
        f16* __restrict__ Wt2, u32* __restrict__ bin_cursor) {
    int blk = blockIdx.x, t = threadIdx.x;
    if (blk == 3) {
        for (int i = t; i < NBIN; i += 256) bin_cursor[i] = 0;
        return;
    }
    const float* W = (blk == 0) ? W1 : (blk == 1) ? W2 : W3;
    f16* wt = Wt2 + blk * 16384;
    for (int idx = t; idx < 16384; idx += 256) {
        int e    = idx & 7;
        int lane = (idx >> 3) & 63;
        int kt   = (idx >> 9) & 7;
        int c    = idx >> 12;
        int col  = c * 16 + (lane & 15);
        int k    = kt * 32 + ((lane >> 4) << 3) + e;
        wt[idx] = (f16)W[k * HID + col];
    }
}

// ---------------- fused: LDS-reordered scatter (5B entries) + MFMA gemm ----------------
// period 5: r==4 -> scatter chunk q in [0,1173); else gemm gid=q*4+r (32-row tiles).
__global__ __launch_bounds__(256) void k_scatgemm(
        const int* __restrict__ ei1, const int* __restrict__ ei2, const int* __restrict__ ei3,
        const float* __restrict__ ew1, const float* __restrict__ ew2, const float* __restrict__ ew3,
        u32* __restrict__ bin_cursor, u32* __restrict__ bkt32, u8* __restrict__ bkt8,
        const float* __restrict__ x1, const float* __restrict__ x2, const float* __restrict__ x3,
        const f16* __restrict__ Wt2, __half* __restrict__ h) {
    __shared__ __align__(16) char smem[16896];   // gemm xl 16.9 KB / scatter 16 KB
    int bid = blockIdx.x;
    int q = bid / 5, r = bid - q * 5;
    int t = threadIdx.x;

    if (r == 4) {                   // ---- scatter chunk (q in [0,1173)) ----
        u32* ent32 = (u32*)smem;                   // 2048*4 = 8 KB
        u16* ent16 = (u16*)(smem + 8192);          // 2048*2 = 4 KB
        u32* acnt  = (u32*)(smem + 12288);         // 256
        u32* ascn  = acnt + 256;
        u32* acur  = ascn + 256;
        u32* adel  = acur + 256;
        int cb  = q;
        int br  = cb / CBLK;
        int blk = cb - br * CBLK;
        const int*   ei = (br == 0) ? ei1 : (br == 1) ? ei2 : ei3;
        const float* ew = (br == 0) ? ew1 : (br == 1) ? ew2 : ew3;
        acnt[t] = 0; acur[t] = 0;
        __syncthreads();
        int e0 = blk * 2048;
        int tot = EE - e0; if (tot > 2048) tot = 2048; if (tot < 0) tot = 0;
        u32 dstv[8];
#pragma unroll
        for (int k = 0; k < 8; ++k) {
            int e = e0 + k * 256 + t;
            if (e < EE) {
                dstv[k] = (u32)ei[EE + e];
                atomicAdd(&acnt[dstv[k] >> 8], 1u);
            }
        }
        __syncthreads();
        ascn[t] = acnt[t];
        __syncthreads();
        for (int d = 1; d < 256; d <<= 1) {
            u32 v = (t >= d) ? ascn[t - d] : 0;
            __syncthreads();
            ascn[t] += v;
            __syncthreads();
        }
        if (t < NBKT) {
            u32 cnt = acnt[t];
            u32 base = cnt ? atomicAdd(&bin_cursor[br * NBKT + t], cnt) : 0;
            adel[t] = (u32)(br * NBKT + t) * MAXB + base - (ascn[t] - acnt[t]);
        }
        __syncthreads();
#pragma unroll
        for (int k = 0; k < 8; ++k) {
            int e = e0 + k * 256 + t;
            if (e < EE) {
                u32 dst = dstv[k];
                u32 src = (u32)ei[e];
                u32 bkt = dst >> 8;
                u16 w16 = __half_as_ushort(__float2half(ew[e]));
                u32 rnk = atomicAdd(&acur[bkt], 1u);
                u32 ls  = ascn[bkt] - acnt[bkt] + rnk;
                ent32[ls] = ((u32)w16 << 16) | src;
                ent16[ls] = (u16)((bkt << 8) | (dst & 0xffu));
            }
        }
        __syncthreads();
        for (int i = t; i < tot; i += 256) {
            u32 v32 = ent32[i];
            u32 v16 = ent16[i];
            u32 bkt = v16 >> 8;
            u32 pos = adel[bkt] + i;
            bkt32[pos] = v32;
            bkt8[pos]  = (u8)v16;
        }
        return;
    }

    // ---- gemm: gid in [0, NGEMM), 32-row x 64-col tile ----
    int gid = q * 4 + r;
    if (gid >= NGEMM) return;
    f16 (*xl)[264] = reinterpret_cast<f16(*)[264]>(smem);   // 16896 B
    int b = gid / GB;
    int row_base = (gid - b * GB) * 32;
    const float4* x4 = reinterpret_cast<const float4*>((b == 0) ? x1 : (b == 1) ? x2 : x3);
    const f16* wt2 = Wt2 + b * 16384;
    __half* hb = h + (size_t)b * NN * HID;

    float4 v[8];
#pragma unroll
    for (int j = 0; j < 8; ++j) {
        int flat = j * 256 + t;
        int gr = row_base + (flat >> 6);
        v[j] = (gr < NN) ? x4[(size_t)row_base * 64 + flat]
                         : make_float4(0.f, 0.f, 0.f, 0.f);
    }
#pragma unroll
    for (int j = 0; j < 8; ++j) {
        int flat = j * 256 + t;
        int rr = flat >> 6, c4 = flat & 63;
        f16x4 p = {(f16)v[j].x, (f16)v[j].y, (f16)v[j].z, (f16)v[j].w};
        *(f16x4*)&xl[rr][c4 * 4] = p;
    }
    __syncthreads();

    int w      = t >> 6;
    int lane   = t & 63;
    int lrow   = lane & 15;
    int lk     = (lane >> 4) * 8;
    int rloc   = (w & 1) * 16;
    int ctile0 = (w >> 1) * 2;
    int arow   = rloc + lrow;

    f32x4 acc[2] = {{0,0,0,0},{0,0,0,0}};
#pragma unroll
    for (int kt = 0; kt < 8; ++kt) {
        f16x8 af = *(const f16x8*)&xl[arow][kt * 32 + lk];
#pragma unroll
        for (int ci = 0; ci < 2; ++ci) {
            int c = ctile0 + ci;
            f16x8 bf = *(const f16x8*)&wt2[((c * 8 + kt) * 64 + lane) * 8];
            acc[ci] = __builtin_amdgcn_mfma_f32_16x16x32_f16(af, bf, acc[ci], 0, 0, 0);
        }
    }
    // LDS-transpose the 32x64 output tile, then one contiguous 4KB write
    __syncthreads();
    __half* hout = (__half*)smem;
#pragma unroll
    for (int ci = 0; ci < 2; ++ci)
#pragma unroll
        for (int i = 0; i < 4; ++i)
            hout[(rloc + ((lane >> 4) << 2) + i) * 64 + (ctile0 + ci) * 16 + lrow] =
                __float2half(acc[ci][i]);
    __syncthreads();
    int rowl = t >> 3;
    int grow = row_base + rowl;
    if (grow < NN)
        ((float4*)(hb + (size_t)grow * HID))[t & 7] = ((const float4*)smem)[t];
}

// ---------------- per-bucket: nodeinfo/dinv/CSR in LDS + h-prescale ----------------
__global__ __launch_bounds__(256) void k_bucket(
        const u32* __restrict__ bkt32, const u8* __restrict__ bkt8,
        const u32* __restrict__ bin_cursor,
        u32* __restrict__ nodeinfo, float* __restrict__ dinv,
        u32* __restrict__ csr, __half* __restrict__ h) {
    __shared__ u32   scnt[256];
    __shared__ float swsum[256];
    __shared__ u32   scur[256];
    __shared__ u32   sscan[256];
    __shared__ float sdiv[256];
    __shared__ u32   lcsr[MAXB];
    int bin = blockIdx.x;
    int br  = bin / NBKT;
    int bkt = bin - br * NBKT;
    int t = threadIdx.x;
    u32 base = (u32)bin * MAXB;
    u32 ecnt = bin_cursor[bin];
    scnt[t] = 0; swsum[t] = 0.f; scur[t] = 0;
    __syncthreads();
    for (u32 i = t; i < ecnt; i += 256) {
        u32 v32 = bkt32[base + i];
        u32 dl  = bkt8[base + i];
        atomicAdd(&scnt[dl], 1u);
        atomicAdd(&swsum[dl], __half2float(__ushort_as_half((u16)(v32 >> 16))));
    }
    __syncthreads();
    sscan[t] = scnt[t];
    __syncthreads();
    for (int d = 1; d < 256; d <<= 1) {
        u32 v = (t >= d) ? sscan[t - d] : 0;
        __syncthreads();
        sscan[t] += v;
        __syncthreads();
    }
    u32 lstart = sscan[t] - scnt[t];
    float d = rsqrtf(1.0f + swsum[t]);
    sdiv[t] = d;
    int n = bkt * 256 + t;
    if (n < NN) {
        int gi = br * NN + n;
        nodeinfo[gi] = ((base + lstart) << 10) | scnt[t];
        dinv[gi]     = d;
    }
    __syncthreads();
    for (u32 i = t; i < ecnt; i += 256) {
        u32 v32 = bkt32[base + i];
        u32 dl  = bkt8[base + i];
        u32 rnk = atomicAdd(&scur[dl], 1u);
        u32 ls  = sscan[dl] - scnt[dl];
        lcsr[ls + rnk] = v32;
    }
    __syncthreads();
    for (u32 i = t; i < ecnt; i += 256) csr[base + i] = lcsr[i];

    int nrows = NN - bkt * 256; if (nrows > 256) nrows = 256;
    u32* hrow = (u32*)(h + ((size_t)br * NN + (size_t)bkt * 256) * HID);
    for (int i = t; i < nrows * 32; i += 256) {
        float dd = sdiv[i >> 5];
        __half2 hv = *(__half2*)&hrow[i];
        float2 v = __half22float2(hv);
        __half2 rr = __float22half2_rn(make_float2(v.x * dd, v.y * dd));
        hrow[i] = *(u32*)&rr;
    }
}

// ---------------- layer-1 aggregation, BRANCH-MAJOR: e = ReLU(...) ----------------
__global__ __launch_bounds__(256) void k_agg1(
        const u32* __restrict__ csr, const u32* __restrict__ nodeinfo,
        const float* __restrict__ dinv,
        const float* __restrict__ b1, const float* __restrict__ b2, const float* __restrict__ b3,
        const __half* __restrict__ h, __half* __restrict__ e) {
    int bid = blockIdx.x;
    int br  = bid / NBLK;
    int nb  = bid - br * NBLK;
    int t   = threadIdx.x;
    int f2  = t & 31;
    int eo  = (t >> 5) & 1;
    int sub = __builtin_amdgcn_readfirstlane(t >> 6);
    int n   = nb * 4 + sub;

    const float* bi = (br == 0) ? b1 : (br == 1) ? b2 : b3;
    const __half2* hb2 = (const __half2*)(h + (size_t)br * NN * HID);
    int i   = br * NN + n;
    u32 inf = nodeinfo[i];
    int cc  = (int)(inf & 1023u);
    int st  = (int)(inf >> 10);
    float d = dinv[i];
    float2 hs = __half22float2(hb2[(size_t)n * 32 + f2]);

    float ax = 0.f, ay = 0.f;
    int cm1 = cc - 1;
    for (int j = 0; j < cc; j += 16) {
        u32 ee[8]; __half2 vv[8];
#pragma unroll
        for (int u = 0; u < 8; ++u) {
            int jj = j + 2 * u + eo;
            ee[u] = csr[st + (jj < cm1 ? jj : cm1)];
            if (jj >= cc) ee[u] &= 0xffffu;
        }
#pragma unroll
        for (int u = 0; u < 8; ++u)
            vv[u] = hb2[(size_t)(ee[u] & 0xffff) * 32 + f2];
#pragma unroll
        for (int u = 0; u < 8; ++u) {
            float w = __half2float(__ushort_as_half((u16)(ee[u] >> 16)));
            float2 v = __half22float2(vv[u]);
            ax = fmaf(w, v.x, ax);
            ay = fmaf(w, v.y, ay);
        }
    }
    ax += __shfl_xor(ax, 32);
    ay += __shfl_xor(ay, 32);
    float2 bv = ((const float2*)bi)[f2];
    float ex = fmaxf(bv.x + d * (hs.x + ax), 0.f);
    float ey = fmaxf(bv.y + d * (hs.y + ay), 0.f);
    if (eo == 0)
        ((__half2*)e)[((size_t)br * NN + n) * 32 + f2] = __float22half2_rn(make_float2(ex, ey));
}

// ---------------- fused attention + layer-2 GEMM (comb stays in LDS) ----------------
__global__ __launch_bounds__(256) void k_attn_gemm2(
        const __half* __restrict__ e,
        const float* __restrict__ fc_w, const float* __restrict__ fc_b,
        const float* __restrict__ W11, const float* __restrict__ W22, const float* __restrict__ W33,
        const float* __restrict__ dinv,
        __half* __restrict__ h2, float* __restrict__ coef_out) {
    __shared__ float Wls[3][HID][OUTF];   // 24 KB
    __shared__ float cls[8][HID];         // 2 KB
    int t = threadIdx.x;
    {
        const float4* w40 = reinterpret_cast<const float4*>(W11);
        const float4* w41 = reinterpret_cast<const float4*>(W22);
        const float4* w42 = reinterpret_cast<const float4*>(W33);
        float4* d0 = reinterpret_cast<float4*>(&Wls[0][0][0]);
        float4* d1 = reinterpret_cast<float4*>(&Wls[1][0][0]);
        float4* d2 = reinterpret_cast<float4*>(&Wls[2][0][0]);
#pragma unroll
        for (int j = 0; j < 2; ++j) {
            d0[t + j * 256] = w40[t + j * 256];
            d1[t + j * 256] = w41[t + j * 256];
            d2[t + j * 256] = w42[t + j * 256];
        }
    }
    int lane = t & 63;
    int sub  = __builtin_amdgcn_readfirstlane(t >> 6);
    int half = lane >> 5;
    int f2   = lane & 31;
    int nl   = sub * 2 + half;                   // node-local 0..7
    int n    = blockIdx.x * 8 + nl;              // 50000 = 6250*8 exact
    float2 wv = ((const float2*)fc_w)[f2];
    float fb = fc_b[0];
    const __half2* e2 = (const __half2*)e;

    float2 ev[3]; float c[3];
#pragma unroll
    for (int b = 0; b < 3; ++b) {
        ev[b] = __half22float2(e2[((size_t)b * NN + n) * 32 + f2]);
        float dd = ev[b].x * wv.x + ev[b].y * wv.y;
#pragma unroll
        for (int off = 16; off > 0; off >>= 1) dd += __shfl_xor(dd, off);
        float z = dd + fb;
        z = (z > 0.f) ? z : 0.01f * z;
        c[b] = expf(z);
    }
    float cd = c[0] + c[1] + c[2];
    float coef0 = c[0] / cd, coef1 = c[1] / cd, coef2 = c[2] / cd;
    cls[nl][2 * f2]     = ev[0].x * coef0 + ev[1].x * coef1 + ev[2].x * coef2;
    cls[nl][2 * f2 + 1] = ev[0].y * coef0 + ev[1].y * coef1 + ev[2].y * coef2;
    if (f2 == 0) {
        coef_out[n]          = coef0;
        coef_out[NN + n]     = coef1;
        coef_out[2 * NN + n] = coef2;
    }
    __syncthreads();

    // gemm2: 8 rows x 3 branches x 32 cols = 768 outputs
    for (int idx = t; idx < 768; idx += 256) {
        int col  = idx & 31;
        int rem  = idx >> 5;            // 0..23
        int br   = rem >> 3;
        int rowl = rem & 7;
        float a = 0.f;
#pragma unroll
        for (int k = 0; k < HID; ++k)
            a = fmaf(cls[rowl][k], Wls[br][k][col], a);
        int row = blockIdx.x * 8 + rowl;
        h2[(size_t)br * NN * OUTF + (size_t)row * OUTF + col] =
            __float2half(a * dinv[br * NN + row]);
    }
}

// ---------------- layer-2 aggregation, BRANCH-MAJOR: partial sums ----------------
__global__ __launch_bounds__(256) void k_agg2p(
        const u32* __restrict__ csr, const u32* __restrict__ nodeinfo,
        const float* __restrict__ dinv,
        const __half* __restrict__ h2, float* __restrict__ outp) {
    int bid = blockIdx.x;
    int br  = bid / NBLK;
    int nb  = bid - br * NBLK;
    int t   = threadIdx.x;
    int f2  = t & 15;
    int eo  = (t >> 4) & 3;
    int sub = __builtin_amdgcn_readfirstlane(t >> 6);
    int n   = nb * 4 + sub;

    int i   = br * NN + n;
    u32 inf = nodeinfo[i];
    int cc  = (int)(inf & 1023u);
    int st  = (int)(inf >> 10);
    const __half2* h2b = (const __half2*)(h2 + (size_t)br * NN * OUTF);
    float ax = 0.f, ay = 0.f;
    int cm1 = cc - 1;
    for (int j = 0; j < cc; j += 16) {
        u32 ee[4]; __half2 vv[4];
#pragma unroll
        for (int u = 0; u < 4; ++u) {
            int jj = j + 4 * u + eo;
            ee[u] = csr[st + (jj < cm1 ? jj : cm1)];
            if (jj >= cc) ee[u] &= 0xffffu;
        }
#pragma unroll
        for (int u = 0; u < 4; ++u)
            vv[u] = h2b[(size_t)(ee[u] & 0xffff) * 16 + f2];
#pragma unroll
        for (int u = 0; u < 4; ++u) {
            float w = __half2float(__ushort_as_half((u16)(ee[u] >> 16)));
            float2 v = __half22float2(vv[u]);
            ax = fmaf(w, v.x, ax);
            ay = fmaf(w, v.y, ay);
        }
    }
    ax += __shfl_xor(ax, 16); ay += __shfl_xor(ay, 16);
    ax += __shfl_xor(ax, 32); ay += __shfl_xor(ay, 32);
    float d = dinv[i];
    float2 hs = __half22float2(h2b[(size_t)n * 16 + f2]);
    if (eo == 0)
        ((float2*)outp)[((size_t)br * NN + n) * 16 + f2] =
            make_float2(d * (ax + hs.x), d * (ay + hs.y));
}

// ---------------- final sum ----------------
__global__ __launch_bounds__(256) void k_sum(
        const float* __restrict__ outp,
        const float* __restrict__ b11, const float* __restrict__ b22, const float* __restrict__ b33,
        float* __restrict__ out) {
    int i = blockIdx.x * 256 + threadIdx.x;
    int f2 = i & 15;
    const float2* p = (const float2*)outp;
    float2 v0 = p[i];
    float2 v1 = p[(size_t)NN * 16 + i];
    float2 v2 = p[(size_t)2 * NN * 16 + i];
    float2 bA = ((const float2*)b11)[f2];
    float2 bB = ((const float2*)b22)[f2];
    float2 bC = ((const float2*)b33)[f2];
    ((float2*)out)[i] = make_float2(v0.x + v1.x + v2.x + bA.x + bB.x + bC.x,
                                    v0.y + v1.y + v2.y + bA.y + bB.y + bC.y);
}

// ---------------- launch ----------------
extern "C" void kernel_launch(void* const* d_in, const int* in_sizes, int n_in,
                              void* d_out, int out_size, void* d_ws, size_t ws_size,
                              hipStream_t stream) {
    const float* x1  = (const float*)d_in[0];
    const float* x2  = (const float*)d_in[1];
    const float* x3  = (const float*)d_in[2];
    const int*   ei1 = (const int*)d_in[3];
    const int*   ei2 = (const int*)d_in[4];
    const int*   ei3 = (const int*)d_in[5];
    const float* ew1 = (const float*)d_in[6];
    const float* ew2 = (const float*)d_in[7];
    const float* ew3 = (const float*)d_in[8];
    const float* W1  = (const float*)d_in[9];
    const float* W2  = (const float*)d_in[10];
    const float* W3  = (const float*)d_in[11];
    const float* b1  = (const float*)d_in[12];
    const float* b2  = (const float*)d_in[13];
    const float* b3  = (const float*)d_in[14];
    const float* fcw = (const float*)d_in[15];
    const float* fcb = (const float*)d_in[16];
    const float* W11 = (const float*)d_in[17];
    const float* W22 = (const float*)d_in[18];
    const float* W33 = (const float*)d_in[19];
    const float* b11 = (const float*)d_in[20];
    const float* b22 = (const float*)d_in[21];
    const float* b33 = (const float*)d_in[22];

    float* out = (float*)d_out;
    float* coef_out = out + (size_t)NN * OUTF;

    // workspace layout; outp aliases e (dead after k_attn_gemm2)
    u32*   bkt32     = (u32*)d_ws;                              // 588*5120 u32 = 12 MB
    u8*    bkt8      = (u8*)(bkt32 + (size_t)NBIN * MAXB);      // 588*5120 u8  =  3 MB
    u32*   csr       = (u32*)(bkt8 + (size_t)NBIN * MAXB + 64); // 12 MB
    u32*   bin_cursor= csr + (size_t)NBIN * MAXB;               // 588
    float* dinv      = (float*)(bin_cursor + NBIN + 4);         // 3N
    u32*   nodeinfo  = (u32*)(dinv + TOTN);                     // 3N
    f16*   Wt2       = (f16*)(nodeinfo + TOTN);                 // 3*16384
    __half* h        = (__half*)(Wt2 + 3 * 16384);              // 3N*64  19.2 MB
    __half* h2       = h + (size_t)TOTN * HID;                  // 3N*32   9.6 MB
    __half* e        = h2 + (size_t)TOTN * OUTF;                // 3N*64  19.2 MB
    float* outp      = (float*)e;                               // 3N*32 f32 (alias)

    k_prep<<<dim3(4), 256, 0, stream>>>(W1, W2, W3, Wt2, bin_cursor);
    k_scatgemm<<<dim3(NCNT * 5), 256, 0, stream>>>(ei1, ei2, ei3, ew1, ew2, ew3,
                                                   bin_cursor, bkt32, bkt8,
                                                   x1, x2, x3, Wt2, h);
    k_bucket<<<dim3(NBIN), 256, 0, stream>>>(bkt32, bkt8, bin_cursor,
                                             nodeinfo, dinv, csr, h);

    k_agg1<<<dim3(3 * NBLK), 256, 0, stream>>>(csr, nodeinfo, dinv, b1, b2, b3, h, e);
    k_attn_gemm2<<<dim3(NN / 8), 256, 0, stream>>>(e, fcw, fcb, W11, W22, W33,
                                                   dinv, h2, coef_out);
    k_agg2p<<<dim3(3 * NBLK), 256, 0, stream>>>(csr, nodeinfo, dinv, h2, outp);
    k_sum<<<dim3(3125), 256, 0, stream>>>(outp, b11, b22, b33, out);
}